// Round 4
// baseline (252.744 us; speedup 1.0000x reference)
//
#include <hip/hip_runtime.h>

#define NSEG 15872
#define DD 129
#define HH 128
#define NTILE (NSEG / 16)  // 992 node tiles

typedef __attribute__((ext_vector_type(8))) short s16x8;
typedef __attribute__((ext_vector_type(4))) short s16x4;
typedef __attribute__((ext_vector_type(4))) float f32x4;
typedef __attribute__((ext_vector_type(16))) float f32x16;
typedef __attribute__((ext_vector_type(4))) unsigned u32x4;

__device__ __forceinline__ unsigned short f2bf(float x) {
  union { float f; unsigned u; } c; c.f = x;
  unsigned r = c.u + 0x7FFFu + ((c.u >> 16) & 1u);
  return (unsigned short)(r >> 16);
}
__device__ __forceinline__ float bf2f(unsigned short v) {
  union { unsigned u; float f; } c; c.u = ((unsigned)v) << 16; return c.f;
}

// ---------------------------------------------------------------------------
// scan_kernel: single block (1024 threads), LDS-staged exclusive scan.
// ---------------------------------------------------------------------------
__global__ __launch_bounds__(1024) void scan_kernel(
    const int* __restrict__ sizes, int* __restrict__ offs) {
  extern __shared__ int dynS[];      // 2 * NSEG ints
  int* szS = dynS;
  int* tmpS = dynS + NSEG;
  __shared__ int sums[1024];
  const int t = threadIdx.x;

  for (int i = t; i < NSEG; i += 1024) szS[i] = sizes[i];
  __syncthreads();

  const int chunk = (NSEG + 1023) >> 10;  // 16
  const int s0 = t * chunk, s1 = min(s0 + chunk, NSEG);
  int s = 0;
  for (int i = s0; i < s1; ++i) s += szS[i];
  sums[t] = s;
  __syncthreads();
  for (int d = 1; d < 1024; d <<= 1) {
    int u = (t >= d) ? sums[t - d] : 0;
    __syncthreads();
    sums[t] += u;
    __syncthreads();
  }
  int a = sums[t] - s;
  for (int i = s0; i < s1; ++i) { tmpS[i] = a; a += szS[i]; }
  __syncthreads();
  for (int i = t; i < NSEG; i += 1024) offs[i] = tmpS[i];
  if (t == 1023) offs[NSEG] = a;
}

// ---------------------------------------------------------------------------
// Packers (x8 vectorized, one s16x8 store per thread).
// ---------------------------------------------------------------------------
__device__ __forceinline__ void packB8(short* out, int idx8, const float* W,
                                       int N, int ld, int ncols, int kLimit,
                                       int rowBase) {
  const int n = (idx8 >> 3) % N;
  const int g = idx8 / (8 * N);
  s16x8 o;
#pragma unroll
  for (int i = 0; i < 8; ++i) {
    const int row = g * 8 + i;
    float v = 0.f;
    if (row < kLimit && n < ncols) v = W[(long)(rowBase + row) * ld + n];
    o[i] = (short)f2bf(v);
  }
  *(s16x8*)(out + idx8) = o;
}

// 32x32x16 A-operand pack of W1n^T: blk = Mblk*10+ks; lane holds
// A[m = Mblk*32 + (lane&31)][k = ks*16 + (lane>>5)*8 + i] = W1[k][m] (0 pad)
__device__ __forceinline__ void packA1T8(short* out, int idx8, const float* W1) {
  const int unit = idx8 >> 3;          // 0..2559
  const int lane = unit & 63;
  const int blk = unit >> 6;           // 0..39
  const int Mblk = blk / 10, ks = blk % 10;
  const int m = Mblk * 32 + (lane & 31);
  const int k0 = ks * 16 + ((lane >> 5) << 3);
  s16x8 o;
#pragma unroll
  for (int i = 0; i < 8; ++i) {
    const int k = k0 + i;
    o[i] = (short)((k < DD) ? f2bf(W1[(long)k * HH + m]) : 0);
  }
  *(s16x8*)(out + idx8) = o;
}

// 32x32x16 B-operand pack of W2: blk = ks*4+nb; lane holds
// B[k = ks*16 + (lane>>5)*8 + i][n = nb*32 + (lane&31)] = W2[k][n]
__device__ __forceinline__ void packB2T8(short* out, int idx8, const float* W2) {
  const int unit = idx8 >> 3;
  const int lane = unit & 63;
  const int blk = unit >> 6;           // 0..31
  const int ks = blk >> 2, nb = blk & 3;
  const int n = nb * 32 + (lane & 31);
  const int k0 = ks * 16 + ((lane >> 5) << 3);
  s16x8 o;
#pragma unroll
  for (int i = 0; i < 8; ++i)
    o[i] = (short)f2bf(W2[(long)(k0 + i) * HH + n]);
  *(s16x8*)(out + idx8) = o;
}

// ---------------------------------------------------------------------------
// pack_tab_kernel: weight packing + bf16 node table (stride 160, zero pad),
// PLUS fused hmprep for block-0 (blocks >= PTBLK).
// ---------------------------------------------------------------------------
#define PACK_IDS 161792  // 40960+32768+36864+40960+10240
#define TAB_IDS (NSEG * 160)
#define PACKV (PACK_IDS / 8)  // 20224
#define TABV (TAB_IDS / 8)    // 317440
#define PTBLK ((PACKV + TABV) / 256)  // 1319
#define HMBLK (NTILE / 4)             // 248
__global__ __launch_bounds__(256) void pack_tab_kernel(
    const float* __restrict__ interp, unsigned short* __restrict__ tab,
    const float* __restrict__ W1b0, const float* __restrict__ W1b1,
    const float* __restrict__ W2b0, const float* __restrict__ W2b1,
    const float* __restrict__ Wob0, const float* __restrict__ Wob1,
    const float* __restrict__ fW1, short* __restrict__ PA1,
    short* __restrict__ PB2, short* __restrict__ PWo,
    short* __restrict__ PW1m, short* __restrict__ PfW1,
    const float* __restrict__ b1, float* __restrict__ Hm) {
  __shared__ short w1s[20480];  // 40 KiB (hm blocks only)
  const int bid = blockIdx.x;
  if (bid >= PTBLK) {
    // ---- fused HM = b1 + bf16(interp) @ W1main (16x16 MFMA) ----
    const int hb = bid - PTBLK;
    for (int u = threadIdx.x; u < 2560; u += 256)
      packB8(w1s, u * 8, W1b0, 128, 128, 128, 129, 129);
    __syncthreads();
    const int lane = threadIdx.x & 63, w = threadIdx.x >> 6;
    const int lk = lane >> 4, n16 = lane & 15;
    const int tile = hb * 4 + w;
    const float* arow = interp + (long)(tile * 16 + n16) * DD;
    s16x8 A[5];
#pragma unroll
    for (int ks = 0; ks < 5; ++ks) {
      s16x8 o;
#pragma unroll
      for (int i = 0; i < 8; ++i) {
        const int k = ks * 32 + lk * 8 + i;
        o[i] = (short)((k < DD) ? f2bf(arow[k]) : 0);
      }
      A[ks] = o;
    }
    f32x4 C[8];
#pragma unroll
    for (int nf = 0; nf < 8; ++nf) C[nf] = (f32x4){0.f, 0.f, 0.f, 0.f};
#pragma unroll
    for (int ks = 0; ks < 5; ++ks)
#pragma unroll
      for (int nf = 0; nf < 8; ++nf) {
        const s16x8 b = *(const s16x8*)(w1s + (((ks * 4 + lk) * 128) + nf * 16 + n16) * 8);
        C[nf] = __builtin_amdgcn_mfma_f32_16x16x32_bf16(A[ks], b, C[nf], 0, 0, 0);
      }
#pragma unroll
    for (int nf = 0; nf < 8; ++nf) {
      const float bv = b1[nf * 16 + n16];
#pragma unroll
      for (int r = 0; r < 4; ++r)
        Hm[(long)(tile * 16 + lk * 4 + r) * HH + nf * 16 + n16] = C[nf][r] + bv;
    }
    return;
  }
  int vid = bid * 256 + threadIdx.x;
  if (vid < PACKV) {
    int idx = vid * 8;
    if (idx < 40960) {  // W1n^T A-frags (32x32x16), K 129->160, M 128
      packA1T8(PA1 + (idx / 20480) * 20480, idx % 20480,
               (idx < 20480) ? W1b0 : W1b1);
      return;
    }
    idx -= 40960;
    if (idx < 32768) {  // W2 B-frags (32x32x16), K 128, N 128
      packB2T8(PB2 + (idx / 16384) * 16384, idx % 16384,
               (idx < 16384) ? W2b0 : W2b1);
      return;
    }
    idx -= 32768;
    if (idx < 36864) {  // Wo (16x16), K 128, N 129->144
      packB8(PWo + (idx / 18432) * 18432, idx % 18432,
             (idx < 18432) ? Wob0 : Wob1, 144, 129, 129, 128, 0);
      return;
    }
    idx -= 36864;
    if (idx < 40960) {  // W1 main half (16x16, rows 129..257), K 129->160
      packB8(PW1m + (idx / 20480) * 20480, idx % 20480,
             (idx < 20480) ? W1b0 : W1b1, 128, 128, 128, 129, 129);
      return;
    }
    idx -= 40960;
    packB8(PfW1, idx, fW1, 64, 64, 64, 129, 0);  // fW1 (16x16) K 129->160
    return;
  }
  vid -= PACKV;
  if (vid < TABV) {
    const int n = vid / 20;
    const int g = vid - n * 20;
    s16x8 o = (s16x8){0, 0, 0, 0, 0, 0, 0, 0};
    if (g < 16) {
      const float* src = interp + (long)n * DD + g * 8;
#pragma unroll
      for (int i = 0; i < 8; ++i) o[i] = (short)f2bf(src[i]);
    } else if (g == 16) {
      o[0] = (short)f2bf(interp[(long)n * DD + 128]);
    }
    *(s16x8*)(tab + (long)vid * 8) = o;
  }
}

// row within a packed pair -> edge index
__device__ __forceinline__ int pairEdge(int row, int oLo, int sLo, int oHi,
                                        int sHi) {
  int e = (row < sLo) ? (oLo + row) : (oHi + row - sLo);
  if (row >= sLo + sHi) e = oHi + sHi - 1;
  return e;
}

// Wave-uniform pair metadata (p is scalarized via readfirstlane -> SGPRs).
struct PairMeta {
  int segLo, segHi, oLo, sLo, oHi, sHi;
};

__device__ __forceinline__ void loadMeta(int p, PairMeta& M,
                                         const int* __restrict__ offs) {
  M.segLo = p;
  M.segHi = NSEG - 1 - p;
  M.oLo = offs[M.segLo]; M.sLo = offs[M.segLo + 1] - M.oLo;
  M.oHi = offs[M.segHi]; M.sHi = offs[M.segHi + 1] - M.oHi;
}

// Scalar prefetch: edge id -> neighbor row + iou (2 VGPR).
__device__ __forceinline__ void prefetchEdge(
    const PairMeta& M, int c, const int* __restrict__ nbrIdx,
    const float* __restrict__ iou, int n32, int& nbrow, float& io) {
  const int grow = (c << 5) + n32;
  const int e = pairEdge(grow, M.oLo, M.sLo, M.oHi, M.sHi);
  nbrow = nbrIdx[e];
  io = iou[e];
}

__device__ __forceinline__ void prefetchHm(
    const PairMeta& M, const float* __restrict__ Hm, int n32,
    float* hmLo, float* hmHi) {
#pragma unroll
  for (int q = 0; q < 4; ++q) {
    hmLo[q] = Hm[(long)M.segLo * HH + q * 32 + n32];
    hmHi[q] = Hm[(long)M.segHi * HH + q * 32 + n32];
  }
}

// ks=9 of the K dimension (k=144..159) is identically zero on BOTH operands
// (A pack zeroes k>=129; tab cols 144..159 are pad) -> 9 frags, not 10.
__device__ __forceinline__ void gatherX(const unsigned short* __restrict__ tab,
                                        int nbrow, int half, s16x8* X) {
  const unsigned short* ar = tab + (long)nbrow * 160;
#pragma unroll
  for (int ks = 0; ks < 9; ++ks)
    X[ks] = *(const s16x8*)(ar + ks * 16 + half * 8);
}

// GEMM1 + bias MFMA + relu + in-register transpose to GEMM2 A-fragments.
// C layout (32x32): col=lane&31 (edge), row=(reg&3)+8(reg>>2)+4*half (feat).
// cvt_pk pairs + 4 v_permlane32_swap_b32 per Mblk redistribute the
// half-wave k-groups into A2[ks][i] = H[edge=lane&31][k=16ks+8*half+i].
// NOTE: io and hmLo/hmHi are DEAD after this returns (consumed into bb/ab)
// — callers overwrite them in place with next-pair prefetches.
__device__ __forceinline__ void gemm1Phase(
    const PairMeta& M, int c, const s16x8* X, float io,
    const short* __restrict__ As1, const float* wvT,
    const float* hmLo, const float* hmHi,
    int lane, int half, int n32, s16x8* A2) {
  const int grow = (c << 5) + n32;
  const short oneBf = (short)0x3F80;
  s16x8 bb = (s16x8){0, 0, 0, 0, 0, 0, 0, 0};
  if (half == 0) {
    const bool lo = grow < M.sLo;
    bb[0] = lo ? oneBf : (short)0;
    bb[1] = bb[0];
    bb[2] = lo ? (short)0 : oneBf;
    bb[3] = bb[2];
    bb[4] = (short)f2bf(io);
  }
#pragma unroll
  for (int Mblk = 0; Mblk < 4; ++Mblk) {
    f32x16 C;
#pragma unroll
    for (int i = 0; i < 16; ++i) C[i] = 0.f;
#pragma unroll
    for (int ks = 0; ks < 9; ++ks) {
      const s16x8 a = *(const s16x8*)(As1 + ((Mblk * 10 + ks) * 64 + lane) * 8);
      C = __builtin_amdgcn_mfma_f32_32x32x16_bf16(a, X[ks], C, 0, 0, 0);
    }
    s16x8 ab = (s16x8){0, 0, 0, 0, 0, 0, 0, 0};
    if (half == 0) {
      const unsigned short p0 = f2bf(hmLo[Mblk]);
      ab[0] = (short)p0;
      ab[1] = (short)f2bf(hmLo[Mblk] - bf2f(p0));
      const unsigned short p1 = f2bf(hmHi[Mblk]);
      ab[2] = (short)p1;
      ab[3] = (short)f2bf(hmHi[Mblk] - bf2f(p1));
      ab[4] = (short)f2bf(wvT[Mblk]);
    }
    C = __builtin_amdgcn_mfma_f32_32x32x16_bf16(ab, bb, C, 0, 0, 0);
    unsigned wv[8];
#pragma unroll
    for (int j = 0; j < 8; ++j) {
      const float lo = fmaxf(C[2 * j], 0.f);
      const float hi = fmaxf(C[2 * j + 1], 0.f);
      asm("v_cvt_pk_bf16_f32 %0, %1, %2" : "=v"(wv[j]) : "v"(lo), "v"(hi));
    }
    asm("v_permlane32_swap_b32 %0, %1" : "+v"(wv[0]), "+v"(wv[2]));
    asm("v_permlane32_swap_b32 %0, %1" : "+v"(wv[1]), "+v"(wv[3]));
    asm("v_permlane32_swap_b32 %0, %1" : "+v"(wv[4]), "+v"(wv[6]));
    asm("v_permlane32_swap_b32 %0, %1" : "+v"(wv[5]), "+v"(wv[7]));
    union { u32x4 u; s16x8 s; } q0, q1;
    q0.u = (u32x4){wv[0], wv[1], wv[2], wv[3]};
    q1.u = (u32x4){wv[4], wv[5], wv[6], wv[7]};
    A2[2 * Mblk] = q0.s;
    A2[2 * Mblk + 1] = q1.s;
  }
}

// GEMM2 + masked segment-split max update (A-fragments come in registers)
__device__ __forceinline__ void gemm2Phase(
    const PairMeta& M, int c, const s16x8* A2, const short* __restrict__ Bs2,
    int lane, int half, int n32, float* mxLo, float* mxHi) {
#pragma unroll
  for (int nb = 0; nb < 4; ++nb) {
    f32x16 D;
#pragma unroll
    for (int i = 0; i < 16; ++i) D[i] = 0.f;
#pragma unroll
    for (int ks = 0; ks < 8; ++ks) {
      const s16x8 b = *(const s16x8*)(Bs2 + ((ks * 4 + nb) * 64 + lane) * 8);
      D = __builtin_amdgcn_mfma_f32_32x32x16_bf16(A2[ks], b, D, 0, 0, 0);
    }
#pragma unroll
    for (int reg = 0; reg < 16; ++reg) {
      const int rrow = (reg & 3) + 8 * (reg >> 2) + 4 * half;
      const int gr = (c << 5) + rrow;
      const float v = D[reg];
      if (gr < M.sLo) mxLo[nb] = fmaxf(mxLo[nb], v);
      else            mxHi[nb] = fmaxf(mxHi[nb], v);
    }
  }
}

// ---------------------------------------------------------------------------
// edge_kernel (32x32x16 MFMA): one segment PAIR = one 32-edge M-tile.
// GEMM1->GEMM2 handoff fully in registers; LDS = packed weights only
// (72 KiB) -> 2 blocks/CU (16 waves). Next-pair prefetch overwrites
// nbrow/io/hmLo/hmHi IN PLACE (dead after gemm1) — no duplicate buffers.
// The rare multi-chunk fallback runs with NO next-pair state live (prefetch
// is deferred past it on that path), keeping the register high-water under
// the 128-reg unified cap on every program point.
// ---------------------------------------------------------------------------
__global__ __launch_bounds__(512, 4) void edge_kernel(
    const unsigned short* __restrict__ tab, const short* __restrict__ PA1,
    const short* __restrict__ PB2, const float* __restrict__ W1,
    const float* __restrict__ Hm, const float* __restrict__ iou,
    const int* __restrict__ nbrIdx, const int* __restrict__ offs,
    const float* __restrict__ b2, unsigned short* __restrict__ pooled) {
  extern __shared__ __align__(16) char smem[];
  short* As1 = (short*)smem;               // 40960 B
  short* Bs2 = (short*)(smem + 40960);     // 32768 B
  {
    const f32x4* s1 = (const f32x4*)PA1;
    f32x4* d1 = (f32x4*)As1;
    for (int i = threadIdx.x; i < 2560; i += 512) d1[i] = s1[i];
    const f32x4* s2 = (const f32x4*)PB2;
    f32x4* d2 = (f32x4*)Bs2;
    for (int i = threadIdx.x; i < 2048; i += 512) d2[i] = s2[i];
  }
  __syncthreads();

  const int lane = threadIdx.x & 63;
  const int w = __builtin_amdgcn_readfirstlane(threadIdx.x >> 6);
  const int half = lane >> 5, n32 = lane & 31;

  float b2v[4], wvT[4];
#pragma unroll
  for (int q = 0; q < 4; ++q) {
    b2v[q] = b2[q * 32 + n32];
    wvT[q] = W1[258 * HH + q * 32 + n32];
  }

  const int wid = (blockIdx.x << 3) + w;   // SGPR
  const int nw = gridDim.x << 3;
  const int npairs = NSEG >> 1;

  if (wid >= npairs) return;

  PairMeta M, Mn;
  int nbrow;
  float io;
  float hmLo[4], hmHi[4];
  loadMeta(wid, M, offs);
  prefetchEdge(M, 0, nbrIdx, iou, n32, nbrow, io);
  prefetchHm(M, Hm, n32, hmLo, hmHi);

  int p = wid;
  for (;;) {
    s16x8 X[9];
    gatherX(tab, nbrow, half, X);
    s16x8 A2[8];
    gemm1Phase(M, 0, X, io, As1, wvT, hmLo, hmHi, lane, half, n32, A2);
    // nbrow/io/hm now dead for this pair
    const int pn = p + nw;
    const bool hn = pn < npairs;                       // scalar
    const bool small = (M.sLo + M.sHi) <= 32;          // scalar
    if (small && hn) {  // hot path: prefetch overlaps GEMM2's MFMA chain
      loadMeta(pn, Mn, offs);
      prefetchEdge(Mn, 0, nbrIdx, iou, n32, nbrow, io);
      prefetchHm(Mn, Hm, n32, hmLo, hmHi);
    }
    float mxLo[4], mxHi[4];
#pragma unroll
    for (int q = 0; q < 4; ++q) { mxLo[q] = -3.4e38f; mxHi[q] = -3.4e38f; }
    gemm2Phase(M, 0, A2, Bs2, lane, half, n32, mxLo, mxHi);
    if (!small) {
      // cold multi-chunk fallback: NO next-pair state live here
      const int nchunk = (M.sLo + M.sHi + 31) >> 5;
      for (int c = 1; c < nchunk; ++c) {
        int nbf; float iof;
        prefetchEdge(M, c, nbrIdx, iou, n32, nbf, iof);
        gatherX(tab, nbf, half, X);
        gemm1Phase(M, c, X, iof, As1, wvT, hmLo, hmHi, lane, half, n32, A2);
        gemm2Phase(M, c, A2, Bs2, lane, half, n32, mxLo, mxHi);
      }
      if (hn) {  // deferred prefetch for next pair
        loadMeta(pn, Mn, offs);
        prefetchEdge(Mn, 0, nbrIdx, iou, n32, nbrow, io);
        prefetchHm(Mn, Hm, n32, hmLo, hmHi);
      }
    }
#pragma unroll
    for (int nb = 0; nb < 4; ++nb) {
      float lo = fmaxf(mxLo[nb], __shfl_xor(mxLo[nb], 32, 64));
      float hi = fmaxf(mxHi[nb], __shfl_xor(mxHi[nb], 32, 64));
      if (half == 0) {
        pooled[(long)M.segLo * HH + nb * 32 + n32] = f2bf(fmaxf(lo + b2v[nb], 0.f));
        pooled[(long)M.segHi * HH + nb * 32 + n32] = f2bf(fmaxf(hi + b2v[nb], 0.f));
      }
    }
    if (!hn) break;
    M = Mn; p = pn;
  }
}

// ---------------------------------------------------------------------------
// resout: RES = resIn + bo + pooled @ Wo (16x16 MFMA). Then via bf16 bounce:
//   NEXT=1: write resOut fp32 + TAB bf16 and compute HM_next = b1n + res@W1m.
//   NEXT=0: fused final head out = relu(res@fW1+fb1)@fW2 + fb2.
// ---------------------------------------------------------------------------
template <int NEXT>
__global__ __launch_bounds__(256) void resout_kernel(
    const unsigned short* __restrict__ pooled, const short* __restrict__ PWo,
    const float* __restrict__ bo, const float* __restrict__ resIn,
    float* __restrict__ resOut, unsigned short* __restrict__ tab,
    const short* __restrict__ PW1mN, const float* __restrict__ b1n,
    float* __restrict__ HmOut,
    const short* __restrict__ PfW1, const float* __restrict__ fb1,
    const float* __restrict__ fW2, const float* __restrict__ fb2,
    float* __restrict__ outFinal) {
  __shared__ short stS[4][16 * 168];
  const int lane = threadIdx.x & 63, w = threadIdx.x >> 6;
  const int lk = lane >> 4, n16 = lane & 15;
  short* st = stS[w];

  {
    const int row = lane >> 2, c0 = 129 + (lane & 3) * 8;
#pragma unroll
    for (int i = 0; i < 8; ++i) st[row * 168 + c0 + i] = 0;
  }

  const int tile = blockIdx.x * 4 + w;
  const unsigned short* arow = pooled + (long)(tile * 16 + n16) * HH;
  s16x8 A[4];
#pragma unroll
  for (int ks = 0; ks < 4; ++ks) A[ks] = *(const s16x8*)(arow + ks * 32 + lk * 8);
  f32x4 C[9];
#pragma unroll
  for (int nf = 0; nf < 9; ++nf) C[nf] = (f32x4){0.f, 0.f, 0.f, 0.f};
#pragma unroll
  for (int ks = 0; ks < 4; ++ks)
#pragma unroll
    for (int nf = 0; nf < 9; ++nf) {
      const s16x8 b = *(const s16x8*)(PWo + (((ks * 4 + lk) * 144) + nf * 16 + n16) * 8);
      C[nf] = __builtin_amdgcn_mfma_f32_16x16x32_bf16(A[ks], b, C[nf], 0, 0, 0);
    }

#pragma unroll
  for (int nf = 0; nf < 8; ++nf) {
    const int col = nf * 16 + n16;
    const float bov = bo[col];
#pragma unroll
    for (int r = 0; r < 4; ++r) {
      const int row = lk * 4 + r;
      const long node = tile * 16 + row;
      const float res = resIn[node * DD + col] + bov + C[nf][r];
      if (NEXT) {
        resOut[node * DD + col] = res;
        tab[node * 160 + col] = f2bf(res);
      }
      st[row * 168 + col] = (short)f2bf(res);
    }
  }
  if (n16 == 0) {
#pragma unroll
    for (int r = 0; r < 4; ++r) {
      const int row = lk * 4 + r;
      const long node = tile * 16 + row;
      const float res = resIn[node * DD + 128] + bo[128] + C[8][r];
      if (NEXT) {
        resOut[node * DD + 128] = res;
        tab[node * 160 + 128] = f2bf(res);
      }
      st[row * 168 + 128] = (short)f2bf(res);
    }
  }

  s16x8 A5[5];
#pragma unroll
  for (int ks = 0; ks < 5; ++ks)
    A5[ks] = *(const s16x8*)(st + n16 * 168 + ks * 32 + lk * 8);

  if (NEXT) {
    f32x4 H[8];
#pragma unroll
    for (int nf = 0; nf < 8; ++nf) H[nf] = (f32x4){0.f, 0.f, 0.f, 0.f};
#pragma unroll
    for (int ks = 0; ks < 5; ++ks)
#pragma unroll
      for (int nf = 0; nf < 8; ++nf) {
        const s16x8 b = *(const s16x8*)(PW1mN + (((ks * 4 + lk) * 128) + nf * 16 + n16) * 8);
        H[nf] = __builtin_amdgcn_mfma_f32_16x16x32_bf16(A5[ks], b, H[nf], 0, 0, 0);
      }
#pragma unroll
    for (int nf = 0; nf < 8; ++nf) {
      const float bv = b1n[nf * 16 + n16];
#pragma unroll
      for (int r = 0; r < 4; ++r)
        HmOut[(long)(tile * 16 + lk * 4 + r) * HH + nf * 16 + n16] = H[nf][r] + bv;
    }
  } else {
    f32x4 Ch[4];
#pragma unroll
    for (int nf = 0; nf < 4; ++nf) Ch[nf] = (f32x4){0.f, 0.f, 0.f, 0.f};
#pragma unroll
    for (int ks = 0; ks < 5; ++ks)
#pragma unroll
      for (int nf = 0; nf < 4; ++nf) {
        const s16x8 b = *(const s16x8*)(PfW1 + (((ks * 4 + lk) * 64) + nf * 16 + n16) * 8);
        Ch[nf] = __builtin_amdgcn_mfma_f32_16x16x32_bf16(A5[ks], b, Ch[nf], 0, 0, 0);
      }
    float b1v[4], w2v[4];
#pragma unroll
    for (int nf = 0; nf < 4; ++nf) {
      b1v[nf] = fb1[nf * 16 + n16];
      w2v[nf] = fW2[nf * 16 + n16];
    }
#pragma unroll
    for (int r = 0; r < 4; ++r) {
      float s = 0.f;
#pragma unroll
      for (int nf = 0; nf < 4; ++nf)
        s += fmaxf(Ch[nf][r] + b1v[nf], 0.f) * w2v[nf];
      s += __shfl_xor(s, 1, 64);
      s += __shfl_xor(s, 2, 64);
      s += __shfl_xor(s, 4, 64);
      s += __shfl_xor(s, 8, 64);
      if (n16 == 0) outFinal[tile * 16 + lk * 4 + r] = s + fb2[0];
    }
  }
}

// ---------------------------------------------------------------------------
extern "C" void kernel_launch(void* const* d_in, const int* in_sizes, int n_in,
                              void* d_out, int out_size, void* d_ws, size_t ws_size,
                              hipStream_t stream) {
  const float* interp  = (const float*)d_in[0];
  const float* addInfo = (const float*)d_in[1];
  const int* sizes     = (const int*)d_in[2];
  const int* nbrIdx    = (const int*)d_in[3];
  const float* b0W1 = (const float*)d_in[5];
  const float* b0b1 = (const float*)d_in[6];
  const float* b0W2 = (const float*)d_in[7];
  const float* b0b2 = (const float*)d_in[8];
  const float* b0Wo = (const float*)d_in[9];
  const float* b0bo = (const float*)d_in[10];
  const float* b1W1 = (const float*)d_in[11];
  const float* b1b1 = (const float*)d_in[12];
  const float* b1W2 = (const float*)d_in[13];
  const float* b1b2 = (const float*)d_in[14];
  const float* b1Wo = (const float*)d_in[15];
  const float* b1bo = (const float*)d_in[16];
  const float* fW1  = (const float*)d_in[17];
  const float* fb1  = (const float*)d_in[18];
  const float* fW2  = (const float*)d_in[19];
  const float* fb2  = (const float*)d_in[20];

  char* ws = (char*)d_ws;
  int*            offs  = (int*)(ws + 0);                    // 65536
  short*          PA1   = (short*)(ws + 65536);              // 81920
  short*          PB2   = (short*)(ws + 147456);             // 65536
  short*          PWo   = (short*)(ws + 212992);             // 73728
  short*          PW1m  = (short*)(ws + 286720);             // 81920
  short*          PfW1  = (short*)(ws + 368640);             // 20480 -> pad
  unsigned short* TAB   = (unsigned short*)(ws + 393216);    // N*160*2
  float*          HM    = (float*)(ws + 5472256);            // N*128*4
  unsigned short* POOLED= (unsigned short*)(ws + 13598720);  // N*128*2
  float*          RES   = (float*)(ws + 17661952);           // N*129*4

  scan_kernel<<<1, 1024, 2 * NSEG * sizeof(int), stream>>>(sizes, offs);
  // pack + tab + fused block-0 hmprep in one dispatch
  pack_tab_kernel<<<PTBLK + HMBLK, 256, 0, stream>>>(
      interp, TAB, b0W1, b1W1, b0W2, b1W2, b0Wo, b1Wo, fW1,
      PA1, PB2, PWo, PW1m, PfW1, b0b1, HM);

  const size_t e_lds = 40960 + 32768;  // 73728 -> 2 blocks/CU

  // ---- block 0 ----
  edge_kernel<<<496, 512, e_lds, stream>>>(TAB, PA1, PB2, b0W1, HM, addInfo,
                                           nbrIdx, offs, b0b2, POOLED);
  resout_kernel<1><<<NTILE / 4, 256, 0, stream>>>(
      POOLED, PWo, b0bo, interp, RES, TAB, PW1m + 20480, b1b1, HM,
      nullptr, nullptr, nullptr, nullptr, nullptr);

  // ---- block 1 ----
  edge_kernel<<<496, 512, e_lds, stream>>>(TAB, PA1 + 20480, PB2 + 16384, b1W1,
                                           HM, addInfo, nbrIdx, offs,
                                           b1b2, POOLED);
  resout_kernel<0><<<NTILE / 4, 256, 0, stream>>>(
      POOLED, PWo + 18432, b1bo, RES, nullptr, nullptr, nullptr, nullptr,
      nullptr, PfW1, fb1, fW2, fb2, (float*)d_out);
}

// Round 5
// 201.128 us; speedup vs baseline: 1.2566x; 1.2566x over previous
//
#include <hip/hip_runtime.h>

#define NSEG 15872
#define DD 129
#define HH 128
#define NTILE (NSEG / 16)  // 992 node tiles

typedef __attribute__((ext_vector_type(8))) short s16x8;
typedef __attribute__((ext_vector_type(4))) short s16x4;
typedef __attribute__((ext_vector_type(4))) float f32x4;
typedef __attribute__((ext_vector_type(16))) float f32x16;
typedef __attribute__((ext_vector_type(4))) unsigned u32x4;

__device__ __forceinline__ unsigned short f2bf(float x) {
  union { float f; unsigned u; } c; c.f = x;
  unsigned r = c.u + 0x7FFFu + ((c.u >> 16) & 1u);
  return (unsigned short)(r >> 16);
}
__device__ __forceinline__ float bf2f(unsigned short v) {
  union { unsigned u; float f; } c; c.u = ((unsigned)v) << 16; return c.f;
}

// ---------------------------------------------------------------------------
// scan_kernel: single block (1024 threads), LDS-staged exclusive scan.
// ---------------------------------------------------------------------------
__global__ __launch_bounds__(1024) void scan_kernel(
    const int* __restrict__ sizes, int* __restrict__ offs) {
  extern __shared__ int dynS[];      // 2 * NSEG ints
  int* szS = dynS;
  int* tmpS = dynS + NSEG;
  __shared__ int sums[1024];
  const int t = threadIdx.x;

  for (int i = t; i < NSEG; i += 1024) szS[i] = sizes[i];
  __syncthreads();

  const int chunk = (NSEG + 1023) >> 10;  // 16
  const int s0 = t * chunk, s1 = min(s0 + chunk, NSEG);
  int s = 0;
  for (int i = s0; i < s1; ++i) s += szS[i];
  sums[t] = s;
  __syncthreads();
  for (int d = 1; d < 1024; d <<= 1) {
    int u = (t >= d) ? sums[t - d] : 0;
    __syncthreads();
    sums[t] += u;
    __syncthreads();
  }
  int a = sums[t] - s;
  for (int i = s0; i < s1; ++i) { tmpS[i] = a; a += szS[i]; }
  __syncthreads();
  for (int i = t; i < NSEG; i += 1024) offs[i] = tmpS[i];
  if (t == 1023) offs[NSEG] = a;
}

// ---------------------------------------------------------------------------
// Packers (x8 vectorized, one s16x8 store per thread).
// ---------------------------------------------------------------------------
__device__ __forceinline__ void packB8(short* out, int idx8, const float* W,
                                       int N, int ld, int ncols, int kLimit,
                                       int rowBase) {
  const int n = (idx8 >> 3) % N;
  const int g = idx8 / (8 * N);
  s16x8 o;
#pragma unroll
  for (int i = 0; i < 8; ++i) {
    const int row = g * 8 + i;
    float v = 0.f;
    if (row < kLimit && n < ncols) v = W[(long)(rowBase + row) * ld + n];
    o[i] = (short)f2bf(v);
  }
  *(s16x8*)(out + idx8) = o;
}

// 32x32x16 A-operand pack of W1n^T: blk = Mblk*10+ks; lane holds
// A[m = Mblk*32 + (lane&31)][k = ks*16 + (lane>>5)*8 + i] = W1[k][m] (0 pad)
__device__ __forceinline__ void packA1T8(short* out, int idx8, const float* W1) {
  const int unit = idx8 >> 3;          // 0..2559
  const int lane = unit & 63;
  const int blk = unit >> 6;           // 0..39
  const int Mblk = blk / 10, ks = blk % 10;
  const int m = Mblk * 32 + (lane & 31);
  const int k0 = ks * 16 + ((lane >> 5) << 3);
  s16x8 o;
#pragma unroll
  for (int i = 0; i < 8; ++i) {
    const int k = k0 + i;
    o[i] = (short)((k < DD) ? f2bf(W1[(long)k * HH + m]) : 0);
  }
  *(s16x8*)(out + idx8) = o;
}

// 32x32x16 B-operand pack of W2: blk = ks*4+nb; lane holds
// B[k = ks*16 + (lane>>5)*8 + i][n = nb*32 + (lane&31)] = W2[k][n]
__device__ __forceinline__ void packB2T8(short* out, int idx8, const float* W2) {
  const int unit = idx8 >> 3;
  const int lane = unit & 63;
  const int blk = unit >> 6;           // 0..31
  const int ks = blk >> 2, nb = blk & 3;
  const int n = nb * 32 + (lane & 31);
  const int k0 = ks * 16 + ((lane >> 5) << 3);
  s16x8 o;
#pragma unroll
  for (int i = 0; i < 8; ++i)
    o[i] = (short)f2bf(W2[(long)(k0 + i) * HH + n]);
  *(s16x8*)(out + idx8) = o;
}

// ---------------------------------------------------------------------------
// pack_tab_kernel: weight packing + bf16 node table (stride 160, zero pad),
// PLUS fused hmprep for block-0 (blocks >= PTBLK).
// ---------------------------------------------------------------------------
#define PACK_IDS 161792  // 40960+32768+36864+40960+10240
#define TAB_IDS (NSEG * 160)
#define PACKV (PACK_IDS / 8)  // 20224
#define TABV (TAB_IDS / 8)    // 317440
#define PTBLK ((PACKV + TABV) / 256)  // 1319
#define HMBLK (NTILE / 4)             // 248
__global__ __launch_bounds__(256) void pack_tab_kernel(
    const float* __restrict__ interp, unsigned short* __restrict__ tab,
    const float* __restrict__ W1b0, const float* __restrict__ W1b1,
    const float* __restrict__ W2b0, const float* __restrict__ W2b1,
    const float* __restrict__ Wob0, const float* __restrict__ Wob1,
    const float* __restrict__ fW1, short* __restrict__ PA1,
    short* __restrict__ PB2, short* __restrict__ PWo,
    short* __restrict__ PW1m, short* __restrict__ PfW1,
    const float* __restrict__ b1, float* __restrict__ Hm) {
  __shared__ short w1s[20480];  // 40 KiB (hm blocks only)
  const int bid = blockIdx.x;
  if (bid >= PTBLK) {
    // ---- fused HM = b1 + bf16(interp) @ W1main (16x16 MFMA) ----
    const int hb = bid - PTBLK;
    for (int u = threadIdx.x; u < 2560; u += 256)
      packB8(w1s, u * 8, W1b0, 128, 128, 128, 129, 129);
    __syncthreads();
    const int lane = threadIdx.x & 63, w = threadIdx.x >> 6;
    const int lk = lane >> 4, n16 = lane & 15;
    const int tile = hb * 4 + w;
    const float* arow = interp + (long)(tile * 16 + n16) * DD;
    s16x8 A[5];
#pragma unroll
    for (int ks = 0; ks < 5; ++ks) {
      s16x8 o;
#pragma unroll
      for (int i = 0; i < 8; ++i) {
        const int k = ks * 32 + lk * 8 + i;
        o[i] = (short)((k < DD) ? f2bf(arow[k]) : 0);
      }
      A[ks] = o;
    }
    f32x4 C[8];
#pragma unroll
    for (int nf = 0; nf < 8; ++nf) C[nf] = (f32x4){0.f, 0.f, 0.f, 0.f};
#pragma unroll
    for (int ks = 0; ks < 5; ++ks)
#pragma unroll
      for (int nf = 0; nf < 8; ++nf) {
        const s16x8 b = *(const s16x8*)(w1s + (((ks * 4 + lk) * 128) + nf * 16 + n16) * 8);
        C[nf] = __builtin_amdgcn_mfma_f32_16x16x32_bf16(A[ks], b, C[nf], 0, 0, 0);
      }
#pragma unroll
    for (int nf = 0; nf < 8; ++nf) {
      const float bv = b1[nf * 16 + n16];
#pragma unroll
      for (int r = 0; r < 4; ++r)
        Hm[(long)(tile * 16 + lk * 4 + r) * HH + nf * 16 + n16] = C[nf][r] + bv;
    }
    return;
  }
  int vid = bid * 256 + threadIdx.x;
  if (vid < PACKV) {
    int idx = vid * 8;
    if (idx < 40960) {  // W1n^T A-frags (32x32x16), K 129->160, M 128
      packA1T8(PA1 + (idx / 20480) * 20480, idx % 20480,
               (idx < 20480) ? W1b0 : W1b1);
      return;
    }
    idx -= 40960;
    if (idx < 32768) {  // W2 B-frags (32x32x16), K 128, N 128
      packB2T8(PB2 + (idx / 16384) * 16384, idx % 16384,
               (idx < 16384) ? W2b0 : W2b1);
      return;
    }
    idx -= 32768;
    if (idx < 36864) {  // Wo (16x16), K 128, N 129->144
      packB8(PWo + (idx / 18432) * 18432, idx % 18432,
             (idx < 18432) ? Wob0 : Wob1, 144, 129, 129, 128, 0);
      return;
    }
    idx -= 36864;
    if (idx < 40960) {  // W1 main half (16x16, rows 129..257), K 129->160
      packB8(PW1m + (idx / 20480) * 20480, idx % 20480,
             (idx < 20480) ? W1b0 : W1b1, 128, 128, 128, 129, 129);
      return;
    }
    idx -= 40960;
    packB8(PfW1, idx, fW1, 64, 64, 64, 129, 0);  // fW1 (16x16) K 129->160
    return;
  }
  vid -= PACKV;
  if (vid < TABV) {
    const int n = vid / 20;
    const int g = vid - n * 20;
    s16x8 o = (s16x8){0, 0, 0, 0, 0, 0, 0, 0};
    if (g < 16) {
      const float* src = interp + (long)n * DD + g * 8;
#pragma unroll
      for (int i = 0; i < 8; ++i) o[i] = (short)f2bf(src[i]);
    } else if (g == 16) {
      o[0] = (short)f2bf(interp[(long)n * DD + 128]);
    }
    *(s16x8*)(tab + (long)vid * 8) = o;
  }
}

// row within a packed pair -> edge index
__device__ __forceinline__ int pairEdge(int row, int oLo, int sLo, int oHi,
                                        int sHi) {
  int e = (row < sLo) ? (oLo + row) : (oHi + row - sLo);
  if (row >= sLo + sHi) e = oHi + sHi - 1;
  return e;
}

// Wave-uniform pair metadata (p is scalarized via readfirstlane -> SGPRs).
struct PairMeta {
  int segLo, segHi, oLo, sLo, oHi, sHi;
};

__device__ __forceinline__ void loadMeta(int p, PairMeta& M,
                                         const int* __restrict__ offs) {
  M.segLo = p;
  M.segHi = NSEG - 1 - p;
  M.oLo = offs[M.segLo]; M.sLo = offs[M.segLo + 1] - M.oLo;
  M.oHi = offs[M.segHi]; M.sHi = offs[M.segHi + 1] - M.oHi;
}

// Scalar prefetch: edge id -> neighbor row + iou (2 VGPR).
__device__ __forceinline__ void prefetchEdge(
    const PairMeta& M, int c, const int* __restrict__ nbrIdx,
    const float* __restrict__ iou, int n32, int& nbrow, float& io) {
  const int grow = (c << 5) + n32;
  const int e = pairEdge(grow, M.oLo, M.sLo, M.oHi, M.sHi);
  nbrow = nbrIdx[e];
  io = iou[e];
}

__device__ __forceinline__ void prefetchHm(
    const PairMeta& M, const float* __restrict__ Hm, int n32,
    float* hmLo, float* hmHi) {
#pragma unroll
  for (int q = 0; q < 4; ++q) {
    hmLo[q] = Hm[(long)M.segLo * HH + q * 32 + n32];
    hmHi[q] = Hm[(long)M.segHi * HH + q * 32 + n32];
  }
}

// ks=9 of the K dimension (k=144..159) is identically zero on BOTH operands
// (A pack zeroes k>=129; tab cols 144..159 are pad) -> 9 frags, not 10.
__device__ __forceinline__ void gatherX(const unsigned short* __restrict__ tab,
                                        int nbrow, int half, s16x8* X) {
  const unsigned short* ar = tab + (long)nbrow * 160;
#pragma unroll
  for (int ks = 0; ks < 9; ++ks)
    X[ks] = *(const s16x8*)(ar + ks * 16 + half * 8);
}

// GEMM1 + bias MFMA + relu + in-register transpose to GEMM2 A-fragments.
// C layout (32x32): col=lane&31 (edge), row=(reg&3)+8(reg>>2)+4*half (feat).
// cvt_pk pairs + 4 v_permlane32_swap_b32 per Mblk redistribute the
// half-wave k-groups into A2[ks][i] = H[edge=lane&31][k=16ks+8*half+i].
__device__ __forceinline__ void gemm1Phase(
    const PairMeta& M, int c, const s16x8* X, float io,
    const short* __restrict__ As1, const float* wvT,
    const float* hmLo, const float* hmHi,
    int lane, int half, int n32, s16x8* A2) {
  const int grow = (c << 5) + n32;
  const short oneBf = (short)0x3F80;
  s16x8 bb = (s16x8){0, 0, 0, 0, 0, 0, 0, 0};
  if (half == 0) {
    const bool lo = grow < M.sLo;
    bb[0] = lo ? oneBf : (short)0;
    bb[1] = bb[0];
    bb[2] = lo ? (short)0 : oneBf;
    bb[3] = bb[2];
    bb[4] = (short)f2bf(io);
  }
#pragma unroll
  for (int Mblk = 0; Mblk < 4; ++Mblk) {
    f32x16 C;
#pragma unroll
    for (int i = 0; i < 16; ++i) C[i] = 0.f;
#pragma unroll
    for (int ks = 0; ks < 9; ++ks) {
      const s16x8 a = *(const s16x8*)(As1 + ((Mblk * 10 + ks) * 64 + lane) * 8);
      C = __builtin_amdgcn_mfma_f32_32x32x16_bf16(a, X[ks], C, 0, 0, 0);
    }
    s16x8 ab = (s16x8){0, 0, 0, 0, 0, 0, 0, 0};
    if (half == 0) {
      const unsigned short p0 = f2bf(hmLo[Mblk]);
      ab[0] = (short)p0;
      ab[1] = (short)f2bf(hmLo[Mblk] - bf2f(p0));
      const unsigned short p1 = f2bf(hmHi[Mblk]);
      ab[2] = (short)p1;
      ab[3] = (short)f2bf(hmHi[Mblk] - bf2f(p1));
      ab[4] = (short)f2bf(wvT[Mblk]);
    }
    C = __builtin_amdgcn_mfma_f32_32x32x16_bf16(ab, bb, C, 0, 0, 0);
    unsigned wv[8];
#pragma unroll
    for (int j = 0; j < 8; ++j) {
      const float lo = fmaxf(C[2 * j], 0.f);
      const float hi = fmaxf(C[2 * j + 1], 0.f);
      asm("v_cvt_pk_bf16_f32 %0, %1, %2" : "=v"(wv[j]) : "v"(lo), "v"(hi));
    }
    asm("v_permlane32_swap_b32 %0, %1" : "+v"(wv[0]), "+v"(wv[2]));
    asm("v_permlane32_swap_b32 %0, %1" : "+v"(wv[1]), "+v"(wv[3]));
    asm("v_permlane32_swap_b32 %0, %1" : "+v"(wv[4]), "+v"(wv[6]));
    asm("v_permlane32_swap_b32 %0, %1" : "+v"(wv[5]), "+v"(wv[7]));
    union { u32x4 u; s16x8 s; } q0, q1;
    q0.u = (u32x4){wv[0], wv[1], wv[2], wv[3]};
    q1.u = (u32x4){wv[4], wv[5], wv[6], wv[7]};
    A2[2 * Mblk] = q0.s;
    A2[2 * Mblk + 1] = q1.s;
  }
}

// GEMM2 + masked segment-split max update (A-fragments come in registers)
__device__ __forceinline__ void gemm2Phase(
    const PairMeta& M, int c, const s16x8* A2, const short* __restrict__ Bs2,
    int lane, int half, int n32, float* mxLo, float* mxHi) {
#pragma unroll
  for (int nb = 0; nb < 4; ++nb) {
    f32x16 D;
#pragma unroll
    for (int i = 0; i < 16; ++i) D[i] = 0.f;
#pragma unroll
    for (int ks = 0; ks < 8; ++ks) {
      const s16x8 b = *(const s16x8*)(Bs2 + ((ks * 4 + nb) * 64 + lane) * 8);
      D = __builtin_amdgcn_mfma_f32_32x32x16_bf16(A2[ks], b, D, 0, 0, 0);
    }
#pragma unroll
    for (int reg = 0; reg < 16; ++reg) {
      const int rrow = (reg & 3) + 8 * (reg >> 2) + 4 * half;
      const int gr = (c << 5) + rrow;
      const float v = D[reg];
      if (gr < M.sLo) mxLo[nb] = fmaxf(mxLo[nb], v);
      else            mxHi[nb] = fmaxf(mxHi[nb], v);
    }
  }
}

// ---------------------------------------------------------------------------
// edge_kernel (32x32x16 MFMA): one segment PAIR = one 32-edge M-tile.
// GEMM1->GEMM2 handoff fully in registers; LDS = packed weights only
// (72 KiB). __launch_bounds__(512, 2): the in-register-transpose structure
// has an irreducible concurrent demand of ~160 unified regs (X36 + A2 32 +
// C/D 16 + hm/mx/addr ~70). Four rounds of data show capping at 128 just
// converts the excess into 56-214 MB of scratch traffic (WRITE_SIZE),
// which costs far more than dropping 4->3 waves/SIMD. Let the allocator
// have ~160-200 regs and spill ZERO; TLP is then ~12 waves/CU.
// ---------------------------------------------------------------------------
__global__ __launch_bounds__(512, 2) void edge_kernel(
    const unsigned short* __restrict__ tab, const short* __restrict__ PA1,
    const short* __restrict__ PB2, const float* __restrict__ W1,
    const float* __restrict__ Hm, const float* __restrict__ iou,
    const int* __restrict__ nbrIdx, const int* __restrict__ offs,
    const float* __restrict__ b2, unsigned short* __restrict__ pooled) {
  extern __shared__ __align__(16) char smem[];
  short* As1 = (short*)smem;               // 40960 B
  short* Bs2 = (short*)(smem + 40960);     // 32768 B
  {
    const f32x4* s1 = (const f32x4*)PA1;
    f32x4* d1 = (f32x4*)As1;
    for (int i = threadIdx.x; i < 2560; i += 512) d1[i] = s1[i];
    const f32x4* s2 = (const f32x4*)PB2;
    f32x4* d2 = (f32x4*)Bs2;
    for (int i = threadIdx.x; i < 2048; i += 512) d2[i] = s2[i];
  }
  __syncthreads();

  const int lane = threadIdx.x & 63;
  const int w = __builtin_amdgcn_readfirstlane(threadIdx.x >> 6);
  const int half = lane >> 5, n32 = lane & 31;

  float b2v[4], wvT[4];
#pragma unroll
  for (int q = 0; q < 4; ++q) {
    b2v[q] = b2[q * 32 + n32];
    wvT[q] = W1[258 * HH + q * 32 + n32];
  }

  const int wid = (blockIdx.x << 3) + w;   // SGPR
  const int nw = gridDim.x << 3;
  const int npairs = NSEG >> 1;

  if (wid >= npairs) return;

  PairMeta M, Mn;
  int nbrow, nbrown;
  float io, ion;
  float hmLo[4], hmHi[4], hmLoN[4], hmHiN[4];
  loadMeta(wid, M, offs);
  prefetchEdge(M, 0, nbrIdx, iou, n32, nbrow, io);
  prefetchHm(M, Hm, n32, hmLo, hmHi);

  int p = wid;
  for (;;) {
    s16x8 X[9];
    gatherX(tab, nbrow, half, X);
    s16x8 A2[8];
    gemm1Phase(M, 0, X, io, As1, wvT, hmLo, hmHi, lane, half, n32, A2);
    // X dead; scalar prefetch for next pair overlaps GEMM2's MFMA chain
    const int pn = p + nw;
    const bool hn = pn < npairs;
    if (hn) {
      loadMeta(pn, Mn, offs);
      prefetchEdge(Mn, 0, nbrIdx, iou, n32, nbrown, ion);
      prefetchHm(Mn, Hm, n32, hmLoN, hmHiN);
    }
    float mxLo[4], mxHi[4];
#pragma unroll
    for (int q = 0; q < 4; ++q) { mxLo[q] = -3.4e38f; mxHi[q] = -3.4e38f; }
    gemm2Phase(M, 0, A2, Bs2, lane, half, n32, mxLo, mxHi);
    if (M.sLo + M.sHi > 32) {
      // cold multi-chunk fallback (reuses X/A2; scalar prefetch unaffected)
      const int nchunk = (M.sLo + M.sHi + 31) >> 5;
      for (int c = 1; c < nchunk; ++c) {
        int nbf; float iof;
        prefetchEdge(M, c, nbrIdx, iou, n32, nbf, iof);
        gatherX(tab, nbf, half, X);
        gemm1Phase(M, c, X, iof, As1, wvT, hmLo, hmHi, lane, half, n32, A2);
        gemm2Phase(M, c, A2, Bs2, lane, half, n32, mxLo, mxHi);
      }
    }
#pragma unroll
    for (int nb = 0; nb < 4; ++nb) {
      float lo = fmaxf(mxLo[nb], __shfl_xor(mxLo[nb], 32, 64));
      float hi = fmaxf(mxHi[nb], __shfl_xor(mxHi[nb], 32, 64));
      if (half == 0) {
        pooled[(long)M.segLo * HH + nb * 32 + n32] = f2bf(fmaxf(lo + b2v[nb], 0.f));
        pooled[(long)M.segHi * HH + nb * 32 + n32] = f2bf(fmaxf(hi + b2v[nb], 0.f));
      }
    }
    if (!hn) break;
    M = Mn; nbrow = nbrown; io = ion;
#pragma unroll
    for (int q = 0; q < 4; ++q) { hmLo[q] = hmLoN[q]; hmHi[q] = hmHiN[q]; }
    p = pn;
  }
}

// ---------------------------------------------------------------------------
// resout: RES = resIn + bo + pooled @ Wo (16x16 MFMA). Then via bf16 bounce:
//   NEXT=1: write resOut fp32 + TAB bf16 and compute HM_next = b1n + res@W1m.
//   NEXT=0: fused final head out = relu(res@fW1+fb1)@fW2 + fb2.
// ---------------------------------------------------------------------------
template <int NEXT>
__global__ __launch_bounds__(256) void resout_kernel(
    const unsigned short* __restrict__ pooled, const short* __restrict__ PWo,
    const float* __restrict__ bo, const float* __restrict__ resIn,
    float* __restrict__ resOut, unsigned short* __restrict__ tab,
    const short* __restrict__ PW1mN, const float* __restrict__ b1n,
    float* __restrict__ HmOut,
    const short* __restrict__ PfW1, const float* __restrict__ fb1,
    const float* __restrict__ fW2, const float* __restrict__ fb2,
    float* __restrict__ outFinal) {
  __shared__ short stS[4][16 * 168];
  const int lane = threadIdx.x & 63, w = threadIdx.x >> 6;
  const int lk = lane >> 4, n16 = lane & 15;
  short* st = stS[w];

  {
    const int row = lane >> 2, c0 = 129 + (lane & 3) * 8;
#pragma unroll
    for (int i = 0; i < 8; ++i) st[row * 168 + c0 + i] = 0;
  }

  const int tile = blockIdx.x * 4 + w;
  const unsigned short* arow = pooled + (long)(tile * 16 + n16) * HH;
  s16x8 A[4];
#pragma unroll
  for (int ks = 0; ks < 4; ++ks) A[ks] = *(const s16x8*)(arow + ks * 32 + lk * 8);
  f32x4 C[9];
#pragma unroll
  for (int nf = 0; nf < 9; ++nf) C[nf] = (f32x4){0.f, 0.f, 0.f, 0.f};
#pragma unroll
  for (int ks = 0; ks < 4; ++ks)
#pragma unroll
    for (int nf = 0; nf < 9; ++nf) {
      const s16x8 b = *(const s16x8*)(PWo + (((ks * 4 + lk) * 144) + nf * 16 + n16) * 8);
      C[nf] = __builtin_amdgcn_mfma_f32_16x16x32_bf16(A[ks], b, C[nf], 0, 0, 0);
    }

#pragma unroll
  for (int nf = 0; nf < 8; ++nf) {
    const int col = nf * 16 + n16;
    const float bov = bo[col];
#pragma unroll
    for (int r = 0; r < 4; ++r) {
      const int row = lk * 4 + r;
      const long node = tile * 16 + row;
      const float res = resIn[node * DD + col] + bov + C[nf][r];
      if (NEXT) {
        resOut[node * DD + col] = res;
        tab[node * 160 + col] = f2bf(res);
      }
      st[row * 168 + col] = (short)f2bf(res);
    }
  }
  if (n16 == 0) {
#pragma unroll
    for (int r = 0; r < 4; ++r) {
      const int row = lk * 4 + r;
      const long node = tile * 16 + row;
      const float res = resIn[node * DD + 128] + bo[128] + C[8][r];
      if (NEXT) {
        resOut[node * DD + 128] = res;
        tab[node * 160 + 128] = f2bf(res);
      }
      st[row * 168 + 128] = (short)f2bf(res);
    }
  }

  s16x8 A5[5];
#pragma unroll
  for (int ks = 0; ks < 5; ++ks)
    A5[ks] = *(const s16x8*)(st + n16 * 168 + ks * 32 + lk * 8);

  if (NEXT) {
    f32x4 H[8];
#pragma unroll
    for (int nf = 0; nf < 8; ++nf) H[nf] = (f32x4){0.f, 0.f, 0.f, 0.f};
#pragma unroll
    for (int ks = 0; ks < 5; ++ks)
#pragma unroll
      for (int nf = 0; nf < 8; ++nf) {
        const s16x8 b = *(const s16x8*)(PW1mN + (((ks * 4 + lk) * 128) + nf * 16 + n16) * 8);
        H[nf] = __builtin_amdgcn_mfma_f32_16x16x32_bf16(A5[ks], b, H[nf], 0, 0, 0);
      }
#pragma unroll
    for (int nf = 0; nf < 8; ++nf) {
      const float bv = b1n[nf * 16 + n16];
#pragma unroll
      for (int r = 0; r < 4; ++r)
        HmOut[(long)(tile * 16 + lk * 4 + r) * HH + nf * 16 + n16] = H[nf][r] + bv;
    }
  } else {
    f32x4 Ch[4];
#pragma unroll
    for (int nf = 0; nf < 4; ++nf) Ch[nf] = (f32x4){0.f, 0.f, 0.f, 0.f};
#pragma unroll
    for (int ks = 0; ks < 5; ++ks)
#pragma unroll
      for (int nf = 0; nf < 4; ++nf) {
        const s16x8 b = *(const s16x8*)(PfW1 + (((ks * 4 + lk) * 64) + nf * 16 + n16) * 8);
        Ch[nf] = __builtin_amdgcn_mfma_f32_16x16x32_bf16(A5[ks], b, Ch[nf], 0, 0, 0);
      }
    float b1v[4], w2v[4];
#pragma unroll
    for (int nf = 0; nf < 4; ++nf) {
      b1v[nf] = fb1[nf * 16 + n16];
      w2v[nf] = fW2[nf * 16 + n16];
    }
#pragma unroll
    for (int r = 0; r < 4; ++r) {
      float s = 0.f;
#pragma unroll
      for (int nf = 0; nf < 4; ++nf)
        s += fmaxf(Ch[nf][r] + b1v[nf], 0.f) * w2v[nf];
      s += __shfl_xor(s, 1, 64);
      s += __shfl_xor(s, 2, 64);
      s += __shfl_xor(s, 4, 64);
      s += __shfl_xor(s, 8, 64);
      if (n16 == 0) outFinal[tile * 16 + lk * 4 + r] = s + fb2[0];
    }
  }
}

// ---------------------------------------------------------------------------
extern "C" void kernel_launch(void* const* d_in, const int* in_sizes, int n_in,
                              void* d_out, int out_size, void* d_ws, size_t ws_size,
                              hipStream_t stream) {
  const float* interp  = (const float*)d_in[0];
  const float* addInfo = (const float*)d_in[1];
  const int* sizes     = (const int*)d_in[2];
  const int* nbrIdx    = (const int*)d_in[3];
  const float* b0W1 = (const float*)d_in[5];
  const float* b0b1 = (const float*)d_in[6];
  const float* b0W2 = (const float*)d_in[7];
  const float* b0b2 = (const float*)d_in[8];
  const float* b0Wo = (const float*)d_in[9];
  const float* b0bo = (const float*)d_in[10];
  const float* b1W1 = (const float*)d_in[11];
  const float* b1b1 = (const float*)d_in[12];
  const float* b1W2 = (const float*)d_in[13];
  const float* b1b2 = (const float*)d_in[14];
  const float* b1Wo = (const float*)d_in[15];
  const float* b1bo = (const float*)d_in[16];
  const float* fW1  = (const float*)d_in[17];
  const float* fb1  = (const float*)d_in[18];
  const float* fW2  = (const float*)d_in[19];
  const float* fb2  = (const float*)d_in[20];

  char* ws = (char*)d_ws;
  int*            offs  = (int*)(ws + 0);                    // 65536
  short*          PA1   = (short*)(ws + 65536);              // 81920
  short*          PB2   = (short*)(ws + 147456);             // 65536
  short*          PWo   = (short*)(ws + 212992);             // 73728
  short*          PW1m  = (short*)(ws + 286720);             // 81920
  short*          PfW1  = (short*)(ws + 368640);             // 20480 -> pad
  unsigned short* TAB   = (unsigned short*)(ws + 393216);    // N*160*2
  float*          HM    = (float*)(ws + 5472256);            // N*128*4
  unsigned short* POOLED= (unsigned short*)(ws + 13598720);  // N*128*2
  float*          RES   = (float*)(ws + 17661952);           // N*129*4

  scan_kernel<<<1, 1024, 2 * NSEG * sizeof(int), stream>>>(sizes, offs);
  // pack + tab + fused block-0 hmprep in one dispatch
  pack_tab_kernel<<<PTBLK + HMBLK, 256, 0, stream>>>(
      interp, TAB, b0W1, b1W1, b0W2, b1W2, b0Wo, b1Wo, fW1,
      PA1, PB2, PWo, PW1m, PfW1, b0b1, HM);

  const size_t e_lds = 40960 + 32768;  // 73728

  // ---- block 0 ----
  edge_kernel<<<496, 512, e_lds, stream>>>(TAB, PA1, PB2, b0W1, HM, addInfo,
                                           nbrIdx, offs, b0b2, POOLED);
  resout_kernel<1><<<NTILE / 4, 256, 0, stream>>>(
      POOLED, PWo, b0bo, interp, RES, TAB, PW1m + 20480, b1b1, HM,
      nullptr, nullptr, nullptr, nullptr, nullptr);

  // ---- block 1 ----
  edge_kernel<<<496, 512, e_lds, stream>>>(TAB, PA1 + 20480, PB2 + 16384, b1W1,
                                           HM, addInfo, nbrIdx, offs,
                                           b1b2, POOLED);
  resout_kernel<0><<<NTILE / 4, 256, 0, stream>>>(
      POOLED, PWo + 18432, b1bo, RES, nullptr, nullptr, nullptr, nullptr,
      nullptr, PfW1, fb1, fW2, fb2, (float*)d_out);
}

// Round 6
// 180.267 us; speedup vs baseline: 1.4021x; 1.1157x over previous
//
#include <hip/hip_runtime.h>

#define NSEG 15872
#define DD 129
#define HH 128
#define NTILE (NSEG / 16)  // 992 node tiles

typedef __attribute__((ext_vector_type(8))) short s16x8;
typedef __attribute__((ext_vector_type(4))) short s16x4;
typedef __attribute__((ext_vector_type(4))) float f32x4;
typedef __attribute__((ext_vector_type(16))) float f32x16;
typedef __attribute__((ext_vector_type(4))) unsigned u32x4;

__device__ __forceinline__ unsigned short f2bf(float x) {
  union { float f; unsigned u; } c; c.f = x;
  unsigned r = c.u + 0x7FFFu + ((c.u >> 16) & 1u);
  return (unsigned short)(r >> 16);
}
__device__ __forceinline__ float bf2f(unsigned short v) {
  union { unsigned u; float f; } c; c.u = ((unsigned)v) << 16; return c.f;
}

// ---------------------------------------------------------------------------
// Packers (x8 vectorized, one s16x8 store per thread).
// ---------------------------------------------------------------------------
__device__ __forceinline__ void packB8(short* out, int idx8, const float* W,
                                       int N, int ld, int ncols, int kLimit,
                                       int rowBase) {
  const int n = (idx8 >> 3) % N;
  const int g = idx8 / (8 * N);
  s16x8 o;
#pragma unroll
  for (int i = 0; i < 8; ++i) {
    const int row = g * 8 + i;
    float v = 0.f;
    if (row < kLimit && n < ncols) v = W[(long)(rowBase + row) * ld + n];
    o[i] = (short)f2bf(v);
  }
  *(s16x8*)(out + idx8) = o;
}

// 32x32x16 A-operand pack of W1n^T: blk = Mblk*10+ks; lane holds
// A[m = Mblk*32 + (lane&31)][k = ks*16 + (lane>>5)*8 + i] = W1[k][m] (0 pad)
__device__ __forceinline__ void packA1T8(short* out, int idx8, const float* W1) {
  const int unit = idx8 >> 3;          // 0..2559
  const int lane = unit & 63;
  const int blk = unit >> 6;           // 0..39
  const int Mblk = blk / 10, ks = blk % 10;
  const int m = Mblk * 32 + (lane & 31);
  const int k0 = ks * 16 + ((lane >> 5) << 3);
  s16x8 o;
#pragma unroll
  for (int i = 0; i < 8; ++i) {
    const int k = k0 + i;
    o[i] = (short)((k < DD) ? f2bf(W1[(long)k * HH + m]) : 0);
  }
  *(s16x8*)(out + idx8) = o;
}

// 32x32x16 B-operand pack of W2: blk = ks*4+nb; lane holds
// B[k = ks*16 + (lane>>5)*8 + i][n = nb*32 + (lane&31)] = W2[k][n]
__device__ __forceinline__ void packB2T8(short* out, int idx8, const float* W2) {
  const int unit = idx8 >> 3;
  const int lane = unit & 63;
  const int blk = unit >> 6;           // 0..31
  const int ks = blk >> 2, nb = blk & 3;
  const int n = nb * 32 + (lane & 31);
  const int k0 = ks * 16 + ((lane >> 5) << 3);
  s16x8 o;
#pragma unroll
  for (int i = 0; i < 8; ++i)
    o[i] = (short)f2bf(W2[(long)(k0 + i) * HH + n]);
  *(s16x8*)(out + idx8) = o;
}

// ---------------------------------------------------------------------------
// pack_tab_kernel: weight packing + bf16 node table (stride 160, zero pad)
// + fused block-0 hmprep (blocks PTBLK..PTBLK+HMBLK-1)
// + fused size-scan (last block; 2-pass over sizes, 1KB LDS) — removes the
//   separate scan launch; edge waits on this dispatch anyway.
// ---------------------------------------------------------------------------
#define PACK_IDS 161792  // 40960+32768+36864+40960+10240
#define TAB_IDS (NSEG * 160)
#define PACKV (PACK_IDS / 8)  // 20224
#define TABV (TAB_IDS / 8)    // 317440
#define PTBLK ((PACKV + TABV) / 256)  // 1319
#define HMBLK (NTILE / 4)             // 248
__global__ __launch_bounds__(256) void pack_tab_kernel(
    const float* __restrict__ interp, unsigned short* __restrict__ tab,
    const float* __restrict__ W1b0, const float* __restrict__ W1b1,
    const float* __restrict__ W2b0, const float* __restrict__ W2b1,
    const float* __restrict__ Wob0, const float* __restrict__ Wob1,
    const float* __restrict__ fW1, short* __restrict__ PA1,
    short* __restrict__ PB2, short* __restrict__ PWo,
    short* __restrict__ PW1m, short* __restrict__ PfW1,
    const float* __restrict__ b1, float* __restrict__ Hm,
    const int* __restrict__ sizes, int* __restrict__ offs) {
  __shared__ short w1s[20480];  // 40 KiB (hm blocks; aliased by scan block)
  const int bid = blockIdx.x;
  if (bid == PTBLK + HMBLK) {
    // ---- fused exclusive scan of segment sizes (2-pass) ----
    int* sums = (int*)w1s;
    const int t = threadIdx.x;
    const int base = t * (NSEG / 256);  // 62 per thread
    int s = 0;
#pragma unroll 8
    for (int i = 0; i < NSEG / 256; ++i) s += sizes[base + i];
    sums[t] = s;
    __syncthreads();
    for (int d = 1; d < 256; d <<= 1) {
      int u = (t >= d) ? sums[t - d] : 0;
      __syncthreads();
      sums[t] += u;
      __syncthreads();
    }
    int a = sums[t] - s;
#pragma unroll 8
    for (int i = 0; i < NSEG / 256; ++i) {
      const int sz = sizes[base + i];
      offs[base + i] = a;
      a += sz;
    }
    if (t == 255) offs[NSEG] = a;
    return;
  }
  if (bid >= PTBLK) {
    // ---- fused HM = b1 + bf16(interp) @ W1main (16x16 MFMA) ----
    const int hb = bid - PTBLK;
    for (int u = threadIdx.x; u < 2560; u += 256)
      packB8(w1s, u * 8, W1b0, 128, 128, 128, 129, 129);
    __syncthreads();
    const int lane = threadIdx.x & 63, w = threadIdx.x >> 6;
    const int lk = lane >> 4, n16 = lane & 15;
    const int tile = hb * 4 + w;
    const float* arow = interp + (long)(tile * 16 + n16) * DD;
    s16x8 A[5];
#pragma unroll
    for (int ks = 0; ks < 5; ++ks) {
      s16x8 o;
#pragma unroll
      for (int i = 0; i < 8; ++i) {
        const int k = ks * 32 + lk * 8 + i;
        o[i] = (short)((k < DD) ? f2bf(arow[k]) : 0);
      }
      A[ks] = o;
    }
    f32x4 C[8];
#pragma unroll
    for (int nf = 0; nf < 8; ++nf) C[nf] = (f32x4){0.f, 0.f, 0.f, 0.f};
#pragma unroll
    for (int ks = 0; ks < 5; ++ks)
#pragma unroll
      for (int nf = 0; nf < 8; ++nf) {
        const s16x8 b = *(const s16x8*)(w1s + (((ks * 4 + lk) * 128) + nf * 16 + n16) * 8);
        C[nf] = __builtin_amdgcn_mfma_f32_16x16x32_bf16(A[ks], b, C[nf], 0, 0, 0);
      }
#pragma unroll
    for (int nf = 0; nf < 8; ++nf) {
      const float bv = b1[nf * 16 + n16];
#pragma unroll
      for (int r = 0; r < 4; ++r)
        Hm[(long)(tile * 16 + lk * 4 + r) * HH + nf * 16 + n16] = C[nf][r] + bv;
    }
    return;
  }
  int vid = bid * 256 + threadIdx.x;
  if (vid < PACKV) {
    int idx = vid * 8;
    if (idx < 40960) {  // W1n^T A-frags (32x32x16), K 129->160, M 128
      packA1T8(PA1 + (idx / 20480) * 20480, idx % 20480,
               (idx < 20480) ? W1b0 : W1b1);
      return;
    }
    idx -= 40960;
    if (idx < 32768) {  // W2 B-frags (32x32x16), K 128, N 128
      packB2T8(PB2 + (idx / 16384) * 16384, idx % 16384,
               (idx < 16384) ? W2b0 : W2b1);
      return;
    }
    idx -= 32768;
    if (idx < 36864) {  // Wo (16x16), K 128, N 129->144
      packB8(PWo + (idx / 18432) * 18432, idx % 18432,
             (idx < 18432) ? Wob0 : Wob1, 144, 129, 129, 128, 0);
      return;
    }
    idx -= 36864;
    if (idx < 40960) {  // W1 main half (16x16, rows 129..257), K 129->160
      packB8(PW1m + (idx / 20480) * 20480, idx % 20480,
             (idx < 20480) ? W1b0 : W1b1, 128, 128, 128, 129, 129);
      return;
    }
    idx -= 40960;
    packB8(PfW1, idx, fW1, 64, 64, 64, 129, 0);  // fW1 (16x16) K 129->160
    return;
  }
  vid -= PACKV;
  if (vid < TABV) {
    const int n = vid / 20;
    const int g = vid - n * 20;
    s16x8 o = (s16x8){0, 0, 0, 0, 0, 0, 0, 0};
    if (g < 16) {
      const float* src = interp + (long)n * DD + g * 8;
#pragma unroll
      for (int i = 0; i < 8; ++i) o[i] = (short)f2bf(src[i]);
    } else if (g == 16) {
      o[0] = (short)f2bf(interp[(long)n * DD + 128]);
    }
    *(s16x8*)(tab + (long)vid * 8) = o;
  }
}

// row within a packed pair -> edge index
__device__ __forceinline__ int pairEdge(int row, int oLo, int sLo, int oHi,
                                        int sHi) {
  int e = (row < sLo) ? (oLo + row) : (oHi + row - sLo);
  if (row >= sLo + sHi) e = oHi + sHi - 1;
  return e;
}

// Wave-uniform pair metadata (p is scalarized via readfirstlane -> SGPRs).
struct PairMeta {
  int segLo, segHi, oLo, sLo, oHi, sHi;
};

__device__ __forceinline__ void loadMeta(int p, PairMeta& M,
                                         const int* __restrict__ offs) {
  M.segLo = p;
  M.segHi = NSEG - 1 - p;
  M.oLo = offs[M.segLo]; M.sLo = offs[M.segLo + 1] - M.oLo;
  M.oHi = offs[M.segHi]; M.sHi = offs[M.segHi + 1] - M.oHi;
}

// Scalar prefetch: edge id -> neighbor row + iou (2 VGPR).
__device__ __forceinline__ void prefetchEdge(
    const PairMeta& M, int c, const int* __restrict__ nbrIdx,
    const float* __restrict__ iou, int n32, int& nbrow, float& io) {
  const int grow = (c << 5) + n32;
  const int e = pairEdge(grow, M.oLo, M.sLo, M.oHi, M.sHi);
  nbrow = nbrIdx[e];
  io = iou[e];
}

__device__ __forceinline__ void prefetchHm(
    const PairMeta& M, const float* __restrict__ Hm, int n32,
    float* hmLo, float* hmHi) {
#pragma unroll
  for (int q = 0; q < 4; ++q) {
    hmLo[q] = Hm[(long)M.segLo * HH + q * 32 + n32];
    hmHi[q] = Hm[(long)M.segHi * HH + q * 32 + n32];
  }
}

// ks=9 of the K dimension (k=144..159) is identically zero on BOTH operands
// (A pack zeroes k>=129; tab cols 144..159 are pad) -> 9 frags, not 10.
__device__ __forceinline__ void gatherX(const unsigned short* __restrict__ tab,
                                        int nbrow, int half, s16x8* X) {
  const unsigned short* ar = tab + (long)nbrow * 160;
#pragma unroll
  for (int ks = 0; ks < 9; ++ks)
    X[ks] = *(const s16x8*)(ar + ks * 16 + half * 8);
}

// GEMM1 + bias MFMA + relu + in-register transpose to GEMM2 A-fragments.
// C layout (32x32): col=lane&31 (edge), row=(reg&3)+8(reg>>2)+4*half (feat).
// cvt_pk pairs + 4 v_permlane32_swap_b32 per Mblk redistribute the
// half-wave k-groups into A2[ks][i] = H[edge=lane&31][k=16ks+8*half+i].
__device__ __forceinline__ void gemm1Phase(
    const PairMeta& M, int c, const s16x8* X, float io,
    const short* __restrict__ As1, const float* wvT,
    const float* hmLo, const float* hmHi,
    int lane, int half, int n32, s16x8* A2) {
  const int grow = (c << 5) + n32;
  const short oneBf = (short)0x3F80;
  s16x8 bb = (s16x8){0, 0, 0, 0, 0, 0, 0, 0};
  if (half == 0) {
    const bool lo = grow < M.sLo;
    bb[0] = lo ? oneBf : (short)0;
    bb[1] = bb[0];
    bb[2] = lo ? (short)0 : oneBf;
    bb[3] = bb[2];
    bb[4] = (short)f2bf(io);
  }
#pragma unroll
  for (int Mblk = 0; Mblk < 4; ++Mblk) {
    f32x16 C;
#pragma unroll
    for (int i = 0; i < 16; ++i) C[i] = 0.f;
#pragma unroll
    for (int ks = 0; ks < 9; ++ks) {
      const s16x8 a = *(const s16x8*)(As1 + ((Mblk * 10 + ks) * 64 + lane) * 8);
      C = __builtin_amdgcn_mfma_f32_32x32x16_bf16(a, X[ks], C, 0, 0, 0);
    }
    s16x8 ab = (s16x8){0, 0, 0, 0, 0, 0, 0, 0};
    if (half == 0) {
      const unsigned short p0 = f2bf(hmLo[Mblk]);
      ab[0] = (short)p0;
      ab[1] = (short)f2bf(hmLo[Mblk] - bf2f(p0));
      const unsigned short p1 = f2bf(hmHi[Mblk]);
      ab[2] = (short)p1;
      ab[3] = (short)f2bf(hmHi[Mblk] - bf2f(p1));
      ab[4] = (short)f2bf(wvT[Mblk]);
    }
    C = __builtin_amdgcn_mfma_f32_32x32x16_bf16(ab, bb, C, 0, 0, 0);
    unsigned wv[8];
#pragma unroll
    for (int j = 0; j < 8; ++j) {
      const float lo = fmaxf(C[2 * j], 0.f);
      const float hi = fmaxf(C[2 * j + 1], 0.f);
      asm("v_cvt_pk_bf16_f32 %0, %1, %2" : "=v"(wv[j]) : "v"(lo), "v"(hi));
    }
    asm("v_permlane32_swap_b32 %0, %1" : "+v"(wv[0]), "+v"(wv[2]));
    asm("v_permlane32_swap_b32 %0, %1" : "+v"(wv[1]), "+v"(wv[3]));
    asm("v_permlane32_swap_b32 %0, %1" : "+v"(wv[4]), "+v"(wv[6]));
    asm("v_permlane32_swap_b32 %0, %1" : "+v"(wv[5]), "+v"(wv[7]));
    union { u32x4 u; s16x8 s; } q0, q1;
    q0.u = (u32x4){wv[0], wv[1], wv[2], wv[3]};
    q1.u = (u32x4){wv[4], wv[5], wv[6], wv[7]};
    A2[2 * Mblk] = q0.s;
    A2[2 * Mblk + 1] = q1.s;
  }
}

// GEMM2 + masked segment-split max update (A-fragments come in registers)
__device__ __forceinline__ void gemm2Phase(
    const PairMeta& M, int c, const s16x8* A2, const short* __restrict__ Bs2,
    int lane, int half, int n32, float* mxLo, float* mxHi) {
#pragma unroll
  for (int nb = 0; nb < 4; ++nb) {
    f32x16 D;
#pragma unroll
    for (int i = 0; i < 16; ++i) D[i] = 0.f;
#pragma unroll
    for (int ks = 0; ks < 8; ++ks) {
      const s16x8 b = *(const s16x8*)(Bs2 + ((ks * 4 + nb) * 64 + lane) * 8);
      D = __builtin_amdgcn_mfma_f32_32x32x16_bf16(A2[ks], b, D, 0, 0, 0);
    }
#pragma unroll
    for (int reg = 0; reg < 16; ++reg) {
      const int rrow = (reg & 3) + 8 * (reg >> 2) + 4 * half;
      const int gr = (c << 5) + rrow;
      const float v = D[reg];
      if (gr < M.sLo) mxLo[nb] = fmaxf(mxLo[nb], v);
      else            mxHi[nb] = fmaxf(mxHi[nb], v);
    }
  }
}

// ---------------------------------------------------------------------------
// edge_kernel (32x32x16 MFMA): one segment PAIR = one 32-edge M-tile.
// (512,2): ~160-200 unified regs, zero spill (proven round 5). Grid 248 =
// exactly 1 block/CU, 4 pairs/wave: one LDS staging per CU and a 4-deep
// software pipeline. The next pair's X gather (9x 64-lane scattered 16B
// loads, the dominant exposed latency) is issued RIGHT AFTER GEMM1 kills
// the current X, hiding it under GEMM2's MFMA+LDS chain — in-place refill,
// no extra register buffer. Only the prologue gather (1 of 4) is exposed.
// ---------------------------------------------------------------------------
__global__ __launch_bounds__(512, 2) void edge_kernel(
    const unsigned short* __restrict__ tab, const short* __restrict__ PA1,
    const short* __restrict__ PB2, const float* __restrict__ W1,
    const float* __restrict__ Hm, const float* __restrict__ iou,
    const int* __restrict__ nbrIdx, const int* __restrict__ offs,
    const float* __restrict__ b2, unsigned short* __restrict__ pooled) {
  extern __shared__ __align__(16) char smem[];
  short* As1 = (short*)smem;               // 40960 B
  short* Bs2 = (short*)(smem + 40960);     // 32768 B
  {
    const f32x4* s1 = (const f32x4*)PA1;
    f32x4* d1 = (f32x4*)As1;
    for (int i = threadIdx.x; i < 2560; i += 512) d1[i] = s1[i];
    const f32x4* s2 = (const f32x4*)PB2;
    f32x4* d2 = (f32x4*)Bs2;
    for (int i = threadIdx.x; i < 2048; i += 512) d2[i] = s2[i];
  }
  __syncthreads();

  const int lane = threadIdx.x & 63;
  const int w = __builtin_amdgcn_readfirstlane(threadIdx.x >> 6);
  const int half = lane >> 5, n32 = lane & 31;

  float b2v[4], wvT[4];
#pragma unroll
  for (int q = 0; q < 4; ++q) {
    b2v[q] = b2[q * 32 + n32];
    wvT[q] = W1[258 * HH + q * 32 + n32];
  }

  const int wid = (blockIdx.x << 3) + w;   // SGPR
  const int nw = gridDim.x << 3;
  const int npairs = NSEG >> 1;

  if (wid >= npairs) return;

  PairMeta M, Mn;
  float io, ioq;
  float hmLo[4], hmHi[4], hmLoN[4], hmHiN[4];
  s16x8 X[9];
  loadMeta(wid, M, offs);
  {
    int nbq;
    prefetchEdge(M, 0, nbrIdx, iou, n32, nbq, io);
    gatherX(tab, nbq, half, X);
  }
  prefetchHm(M, Hm, n32, hmLo, hmHi);

  int p = wid;
  for (;;) {
    s16x8 A2[8];
    gemm1Phase(M, 0, X, io, As1, wvT, hmLo, hmHi, lane, half, n32, A2);
    // X dead -> refill with NEXT pair's gather; hides under GEMM2's chain
    const int pn = p + nw;
    const bool hn = pn < npairs;
    const bool small = (M.sLo + M.sHi) <= 32;
    if (small && hn) {
      loadMeta(pn, Mn, offs);
      int nbq;
      prefetchEdge(Mn, 0, nbrIdx, iou, n32, nbq, ioq);
      prefetchHm(Mn, Hm, n32, hmLoN, hmHiN);
      gatherX(tab, nbq, half, X);
    }
    float mxLo[4], mxHi[4];
#pragma unroll
    for (int q = 0; q < 4; ++q) { mxLo[q] = -3.4e38f; mxHi[q] = -3.4e38f; }
    gemm2Phase(M, 0, A2, Bs2, lane, half, n32, mxLo, mxHi);
    if (!small) {
      // cold multi-chunk fallback: X/A2 free here (prefetch deferred)
      const int nchunk = (M.sLo + M.sHi + 31) >> 5;
      for (int c = 1; c < nchunk; ++c) {
        int nbf; float iof;
        prefetchEdge(M, c, nbrIdx, iou, n32, nbf, iof);
        gatherX(tab, nbf, half, X);
        gemm1Phase(M, c, X, iof, As1, wvT, hmLo, hmHi, lane, half, n32, A2);
        gemm2Phase(M, c, A2, Bs2, lane, half, n32, mxLo, mxHi);
      }
      if (hn) {  // deferred next-pair prefetch + gather
        loadMeta(pn, Mn, offs);
        int nbq;
        prefetchEdge(Mn, 0, nbrIdx, iou, n32, nbq, ioq);
        prefetchHm(Mn, Hm, n32, hmLoN, hmHiN);
        gatherX(tab, nbq, half, X);
      }
    }
#pragma unroll
    for (int nb = 0; nb < 4; ++nb) {
      float lo = fmaxf(mxLo[nb], __shfl_xor(mxLo[nb], 32, 64));
      float hi = fmaxf(mxHi[nb], __shfl_xor(mxHi[nb], 32, 64));
      if (half == 0) {
        pooled[(long)M.segLo * HH + nb * 32 + n32] = f2bf(fmaxf(lo + b2v[nb], 0.f));
        pooled[(long)M.segHi * HH + nb * 32 + n32] = f2bf(fmaxf(hi + b2v[nb], 0.f));
      }
    }
    if (!hn) break;
    M = Mn; io = ioq;
#pragma unroll
    for (int q = 0; q < 4; ++q) { hmLo[q] = hmLoN[q]; hmHi[q] = hmHiN[q]; }
    p = pn;
  }
}

// ---------------------------------------------------------------------------
// resout: RES = resIn + bo + pooled @ Wo (16x16 MFMA). Then via bf16 bounce:
//   NEXT=1: write resOut fp32 + TAB bf16 and compute HM_next = b1n + res@W1m.
//   NEXT=0: fused final head out = relu(res@fW1+fb1)@fW2 + fb2.
// ---------------------------------------------------------------------------
template <int NEXT>
__global__ __launch_bounds__(256) void resout_kernel(
    const unsigned short* __restrict__ pooled, const short* __restrict__ PWo,
    const float* __restrict__ bo, const float* __restrict__ resIn,
    float* __restrict__ resOut, unsigned short* __restrict__ tab,
    const short* __restrict__ PW1mN, const float* __restrict__ b1n,
    float* __restrict__ HmOut,
    const short* __restrict__ PfW1, const float* __restrict__ fb1,
    const float* __restrict__ fW2, const float* __restrict__ fb2,
    float* __restrict__ outFinal) {
  __shared__ short stS[4][16 * 168];
  const int lane = threadIdx.x & 63, w = threadIdx.x >> 6;
  const int lk = lane >> 4, n16 = lane & 15;
  short* st = stS[w];

  {
    const int row = lane >> 2, c0 = 129 + (lane & 3) * 8;
#pragma unroll
    for (int i = 0; i < 8; ++i) st[row * 168 + c0 + i] = 0;
  }

  const int tile = blockIdx.x * 4 + w;
  const unsigned short* arow = pooled + (long)(tile * 16 + n16) * HH;
  s16x8 A[4];
#pragma unroll
  for (int ks = 0; ks < 4; ++ks) A[ks] = *(const s16x8*)(arow + ks * 32 + lk * 8);
  f32x4 C[9];
#pragma unroll
  for (int nf = 0; nf < 9; ++nf) C[nf] = (f32x4){0.f, 0.f, 0.f, 0.f};
#pragma unroll
  for (int ks = 0; ks < 4; ++ks)
#pragma unroll
    for (int nf = 0; nf < 9; ++nf) {
      const s16x8 b = *(const s16x8*)(PWo + (((ks * 4 + lk) * 144) + nf * 16 + n16) * 8);
      C[nf] = __builtin_amdgcn_mfma_f32_16x16x32_bf16(A[ks], b, C[nf], 0, 0, 0);
    }

#pragma unroll
  for (int nf = 0; nf < 8; ++nf) {
    const int col = nf * 16 + n16;
    const float bov = bo[col];
#pragma unroll
    for (int r = 0; r < 4; ++r) {
      const int row = lk * 4 + r;
      const long node = tile * 16 + row;
      const float res = resIn[node * DD + col] + bov + C[nf][r];
      if (NEXT) {
        resOut[node * DD + col] = res;
        tab[node * 160 + col] = f2bf(res);
      }
      st[row * 168 + col] = (short)f2bf(res);
    }
  }
  if (n16 == 0) {
#pragma unroll
    for (int r = 0; r < 4; ++r) {
      const int row = lk * 4 + r;
      const long node = tile * 16 + row;
      const float res = resIn[node * DD + 128] + bo[128] + C[8][r];
      if (NEXT) {
        resOut[node * DD + 128] = res;
        tab[node * 160 + 128] = f2bf(res);
      }
      st[row * 168 + 128] = (short)f2bf(res);
    }
  }

  s16x8 A5[5];
#pragma unroll
  for (int ks = 0; ks < 5; ++ks)
    A5[ks] = *(const s16x8*)(st + n16 * 168 + ks * 32 + lk * 8);

  if (NEXT) {
    f32x4 H[8];
#pragma unroll
    for (int nf = 0; nf < 8; ++nf) H[nf] = (f32x4){0.f, 0.f, 0.f, 0.f};
#pragma unroll
    for (int ks = 0; ks < 5; ++ks)
#pragma unroll
      for (int nf = 0; nf < 8; ++nf) {
        const s16x8 b = *(const s16x8*)(PW1mN + (((ks * 4 + lk) * 128) + nf * 16 + n16) * 8);
        H[nf] = __builtin_amdgcn_mfma_f32_16x16x32_bf16(A5[ks], b, H[nf], 0, 0, 0);
      }
#pragma unroll
    for (int nf = 0; nf < 8; ++nf) {
      const float bv = b1n[nf * 16 + n16];
#pragma unroll
      for (int r = 0; r < 4; ++r)
        HmOut[(long)(tile * 16 + lk * 4 + r) * HH + nf * 16 + n16] = H[nf][r] + bv;
    }
  } else {
    f32x4 Ch[4];
#pragma unroll
    for (int nf = 0; nf < 4; ++nf) Ch[nf] = (f32x4){0.f, 0.f, 0.f, 0.f};
#pragma unroll
    for (int ks = 0; ks < 5; ++ks)
#pragma unroll
      for (int nf = 0; nf < 4; ++nf) {
        const s16x8 b = *(const s16x8*)(PfW1 + (((ks * 4 + lk) * 64) + nf * 16 + n16) * 8);
        Ch[nf] = __builtin_amdgcn_mfma_f32_16x16x32_bf16(A5[ks], b, Ch[nf], 0, 0, 0);
      }
    float b1v[4], w2v[4];
#pragma unroll
    for (int nf = 0; nf < 4; ++nf) {
      b1v[nf] = fb1[nf * 16 + n16];
      w2v[nf] = fW2[nf * 16 + n16];
    }
#pragma unroll
    for (int r = 0; r < 4; ++r) {
      float s = 0.f;
#pragma unroll
      for (int nf = 0; nf < 4; ++nf)
        s += fmaxf(Ch[nf][r] + b1v[nf], 0.f) * w2v[nf];
      s += __shfl_xor(s, 1, 64);
      s += __shfl_xor(s, 2, 64);
      s += __shfl_xor(s, 4, 64);
      s += __shfl_xor(s, 8, 64);
      if (n16 == 0) outFinal[tile * 16 + lk * 4 + r] = s + fb2[0];
    }
  }
}

// ---------------------------------------------------------------------------
extern "C" void kernel_launch(void* const* d_in, const int* in_sizes, int n_in,
                              void* d_out, int out_size, void* d_ws, size_t ws_size,
                              hipStream_t stream) {
  const float* interp  = (const float*)d_in[0];
  const float* addInfo = (const float*)d_in[1];
  const int* sizes     = (const int*)d_in[2];
  const int* nbrIdx    = (const int*)d_in[3];
  const float* b0W1 = (const float*)d_in[5];
  const float* b0b1 = (const float*)d_in[6];
  const float* b0W2 = (const float*)d_in[7];
  const float* b0b2 = (const float*)d_in[8];
  const float* b0Wo = (const float*)d_in[9];
  const float* b0bo = (const float*)d_in[10];
  const float* b1W1 = (const float*)d_in[11];
  const float* b1b1 = (const float*)d_in[12];
  const float* b1W2 = (const float*)d_in[13];
  const float* b1b2 = (const float*)d_in[14];
  const float* b1Wo = (const float*)d_in[15];
  const float* b1bo = (const float*)d_in[16];
  const float* fW1  = (const float*)d_in[17];
  const float* fb1  = (const float*)d_in[18];
  const float* fW2  = (const float*)d_in[19];
  const float* fb2  = (const float*)d_in[20];

  char* ws = (char*)d_ws;
  int*            offs  = (int*)(ws + 0);                    // 65536
  short*          PA1   = (short*)(ws + 65536);              // 81920
  short*          PB2   = (short*)(ws + 147456);             // 65536
  short*          PWo   = (short*)(ws + 212992);             // 73728
  short*          PW1m  = (short*)(ws + 286720);             // 81920
  short*          PfW1  = (short*)(ws + 368640);             // 20480 -> pad
  unsigned short* TAB   = (unsigned short*)(ws + 393216);    // N*160*2
  float*          HM    = (float*)(ws + 5472256);            // N*128*4
  unsigned short* POOLED= (unsigned short*)(ws + 13598720);  // N*128*2
  float*          RES   = (float*)(ws + 17661952);           // N*129*4

  // pack + tab + fused hmprep + fused scan: one dispatch
  pack_tab_kernel<<<PTBLK + HMBLK + 1, 256, 0, stream>>>(
      interp, TAB, b0W1, b1W1, b0W2, b1W2, b0Wo, b1Wo, fW1,
      PA1, PB2, PWo, PW1m, PfW1, b0b1, HM, sizes, offs);

  const size_t e_lds = 40960 + 32768;  // 73728

  // ---- block 0 ----
  edge_kernel<<<248, 512, e_lds, stream>>>(TAB, PA1, PB2, b0W1, HM, addInfo,
                                           nbrIdx, offs, b0b2, POOLED);
  resout_kernel<1><<<NTILE / 4, 256, 0, stream>>>(
      POOLED, PWo, b0bo, interp, RES, TAB, PW1m + 20480, b1b1, HM,
      nullptr, nullptr, nullptr, nullptr, nullptr);

  // ---- block 1 ----
  edge_kernel<<<248, 512, e_lds, stream>>>(TAB, PA1 + 20480, PB2 + 16384, b1W1,
                                           HM, addInfo, nbrIdx, offs,
                                           b1b2, POOLED);
  resout_kernel<0><<<NTILE / 4, 256, 0, stream>>>(
      POOLED, PWo + 18432, b1bo, RES, nullptr, nullptr, nullptr, nullptr,
      nullptr, PfW1, fb1, fW2, fb2, (float*)d_out);
}

// Round 7
// 178.634 us; speedup vs baseline: 1.4149x; 1.0091x over previous
//
#include <hip/hip_runtime.h>

#define NSEG 15872
#define DD 129
#define HH 128
#define NTILE (NSEG / 16)  // 992 node tiles

typedef __attribute__((ext_vector_type(8))) short s16x8;
typedef __attribute__((ext_vector_type(4))) short s16x4;
typedef __attribute__((ext_vector_type(4))) float f32x4;
typedef __attribute__((ext_vector_type(16))) float f32x16;
typedef __attribute__((ext_vector_type(4))) unsigned u32x4;

__device__ __forceinline__ unsigned short f2bf(float x) {
  union { float f; unsigned u; } c; c.f = x;
  unsigned r = c.u + 0x7FFFu + ((c.u >> 16) & 1u);
  return (unsigned short)(r >> 16);
}
__device__ __forceinline__ float bf2f(unsigned short v) {
  union { unsigned u; float f; } c; c.u = ((unsigned)v) << 16; return c.f;
}

// ---------------------------------------------------------------------------
// Packers (x8 vectorized, one s16x8 store per thread).
// ---------------------------------------------------------------------------
__device__ __forceinline__ void packB8(short* out, int idx8, const float* W,
                                       int N, int ld, int ncols, int kLimit,
                                       int rowBase) {
  const int n = (idx8 >> 3) % N;
  const int g = idx8 / (8 * N);
  s16x8 o;
#pragma unroll
  for (int i = 0; i < 8; ++i) {
    const int row = g * 8 + i;
    float v = 0.f;
    if (row < kLimit && n < ncols) v = W[(long)(rowBase + row) * ld + n];
    o[i] = (short)f2bf(v);
  }
  *(s16x8*)(out + idx8) = o;
}

// 32x32x16 A-operand pack of W1n^T: blk = Mblk*10+ks; lane holds
// A[m = Mblk*32 + (lane&31)][k = ks*16 + (lane>>5)*8 + i] = W1[k][m] (0 pad)
__device__ __forceinline__ void packA1T8(short* out, int idx8, const float* W1) {
  const int unit = idx8 >> 3;          // 0..2559
  const int lane = unit & 63;
  const int blk = unit >> 6;           // 0..39
  const int Mblk = blk / 10, ks = blk % 10;
  const int m = Mblk * 32 + (lane & 31);
  const int k0 = ks * 16 + ((lane >> 5) << 3);
  s16x8 o;
#pragma unroll
  for (int i = 0; i < 8; ++i) {
    const int k = k0 + i;
    o[i] = (short)((k < DD) ? f2bf(W1[(long)k * HH + m]) : 0);
  }
  *(s16x8*)(out + idx8) = o;
}

// 32x32x16 B-operand pack of W2: blk = ks*4+nb; lane holds
// B[k = ks*16 + (lane>>5)*8 + i][n = nb*32 + (lane&31)] = W2[k][n]
__device__ __forceinline__ void packB2T8(short* out, int idx8, const float* W2) {
  const int unit = idx8 >> 3;
  const int lane = unit & 63;
  const int blk = unit >> 6;           // 0..31
  const int ks = blk >> 2, nb = blk & 3;
  const int n = nb * 32 + (lane & 31);
  const int k0 = ks * 16 + ((lane >> 5) << 3);
  s16x8 o;
#pragma unroll
  for (int i = 0; i < 8; ++i)
    o[i] = (short)f2bf(W2[(long)(k0 + i) * HH + n]);
  *(s16x8*)(out + idx8) = o;
}

// ---------------------------------------------------------------------------
// pack_tab_kernel: weight packing + bf16 node table (stride 160, zero pad)
// + fused block-0 hmprep (blocks PTBLK..PTBLK+HMBLK-1)
// + fused size-scan (last block).
// ---------------------------------------------------------------------------
#define PACK_IDS 161792  // 40960+32768+36864+40960+10240
#define TAB_IDS (NSEG * 160)
#define PACKV (PACK_IDS / 8)  // 20224
#define TABV (TAB_IDS / 8)    // 317440
#define PTBLK ((PACKV + TABV) / 256)  // 1319
#define HMBLK (NTILE / 4)             // 248
__global__ __launch_bounds__(256) void pack_tab_kernel(
    const float* __restrict__ interp, unsigned short* __restrict__ tab,
    const float* __restrict__ W1b0, const float* __restrict__ W1b1,
    const float* __restrict__ W2b0, const float* __restrict__ W2b1,
    const float* __restrict__ Wob0, const float* __restrict__ Wob1,
    const float* __restrict__ fW1, short* __restrict__ PA1,
    short* __restrict__ PB2, short* __restrict__ PWo,
    short* __restrict__ PW1m, short* __restrict__ PfW1,
    const float* __restrict__ b1, float* __restrict__ Hm,
    const int* __restrict__ sizes, int* __restrict__ offs) {
  __shared__ short w1s[20480];  // 40 KiB (hm blocks; aliased by scan block)
  const int bid = blockIdx.x;
  if (bid == PTBLK + HMBLK) {
    // ---- fused exclusive scan of segment sizes (2-pass) ----
    int* sums = (int*)w1s;
    const int t = threadIdx.x;
    const int base = t * (NSEG / 256);  // 62 per thread
    int s = 0;
#pragma unroll 8
    for (int i = 0; i < NSEG / 256; ++i) s += sizes[base + i];
    sums[t] = s;
    __syncthreads();
    for (int d = 1; d < 256; d <<= 1) {
      int u = (t >= d) ? sums[t - d] : 0;
      __syncthreads();
      sums[t] += u;
      __syncthreads();
    }
    int a = sums[t] - s;
#pragma unroll 8
    for (int i = 0; i < NSEG / 256; ++i) {
      const int sz = sizes[base + i];
      offs[base + i] = a;
      a += sz;
    }
    if (t == 255) offs[NSEG] = a;
    return;
  }
  if (bid >= PTBLK) {
    // ---- fused HM = b1 + bf16(interp) @ W1main (16x16 MFMA) ----
    const int hb = bid - PTBLK;
    for (int u = threadIdx.x; u < 2560; u += 256)
      packB8(w1s, u * 8, W1b0, 128, 128, 128, 129, 129);
    __syncthreads();
    const int lane = threadIdx.x & 63, w = threadIdx.x >> 6;
    const int lk = lane >> 4, n16 = lane & 15;
    const int tile = hb * 4 + w;
    const float* arow = interp + (long)(tile * 16 + n16) * DD;
    s16x8 A[5];
#pragma unroll
    for (int ks = 0; ks < 5; ++ks) {
      s16x8 o;
#pragma unroll
      for (int i = 0; i < 8; ++i) {
        const int k = ks * 32 + lk * 8 + i;
        o[i] = (short)((k < DD) ? f2bf(arow[k]) : 0);
      }
      A[ks] = o;
    }
    f32x4 C[8];
#pragma unroll
    for (int nf = 0; nf < 8; ++nf) C[nf] = (f32x4){0.f, 0.f, 0.f, 0.f};
#pragma unroll
    for (int ks = 0; ks < 5; ++ks)
#pragma unroll
      for (int nf = 0; nf < 8; ++nf) {
        const s16x8 b = *(const s16x8*)(w1s + (((ks * 4 + lk) * 128) + nf * 16 + n16) * 8);
        C[nf] = __builtin_amdgcn_mfma_f32_16x16x32_bf16(A[ks], b, C[nf], 0, 0, 0);
      }
#pragma unroll
    for (int nf = 0; nf < 8; ++nf) {
      const float bv = b1[nf * 16 + n16];
#pragma unroll
      for (int r = 0; r < 4; ++r)
        Hm[(long)(tile * 16 + lk * 4 + r) * HH + nf * 16 + n16] = C[nf][r] + bv;
    }
    return;
  }
  int vid = bid * 256 + threadIdx.x;
  if (vid < PACKV) {
    int idx = vid * 8;
    if (idx < 40960) {  // W1n^T A-frags (32x32x16), K 129->160, M 128
      packA1T8(PA1 + (idx / 20480) * 20480, idx % 20480,
               (idx < 20480) ? W1b0 : W1b1);
      return;
    }
    idx -= 40960;
    if (idx < 32768) {  // W2 B-frags (32x32x16), K 128, N 128
      packB2T8(PB2 + (idx / 16384) * 16384, idx % 16384,
               (idx < 16384) ? W2b0 : W2b1);
      return;
    }
    idx -= 32768;
    if (idx < 36864) {  // Wo (16x16), K 128, N 129->144
      packB8(PWo + (idx / 18432) * 18432, idx % 18432,
             (idx < 18432) ? Wob0 : Wob1, 144, 129, 129, 128, 0);
      return;
    }
    idx -= 36864;
    if (idx < 40960) {  // W1 main half (16x16, rows 129..257), K 129->160
      packB8(PW1m + (idx / 20480) * 20480, idx % 20480,
             (idx < 20480) ? W1b0 : W1b1, 128, 128, 128, 129, 129);
      return;
    }
    idx -= 40960;
    packB8(PfW1, idx, fW1, 64, 64, 64, 129, 0);  // fW1 (16x16) K 129->160
    return;
  }
  vid -= PACKV;
  if (vid < TABV) {
    const int n = vid / 20;
    const int g = vid - n * 20;
    s16x8 o = (s16x8){0, 0, 0, 0, 0, 0, 0, 0};
    if (g < 16) {
      const float* src = interp + (long)n * DD + g * 8;
#pragma unroll
      for (int i = 0; i < 8; ++i) o[i] = (short)f2bf(src[i]);
    } else if (g == 16) {
      o[0] = (short)f2bf(interp[(long)n * DD + 128]);
    }
    *(s16x8*)(tab + (long)vid * 8) = o;
  }
}

// row within a packed pair -> edge index
__device__ __forceinline__ int pairEdge(int row, int oLo, int sLo, int oHi,
                                        int sHi) {
  int e = (row < sLo) ? (oLo + row) : (oHi + row - sLo);
  if (row >= sLo + sHi) e = oHi + sHi - 1;
  return e;
}

// Wave-uniform pair metadata (p is scalarized via readfirstlane -> SGPRs).
struct PairMeta {
  int segLo, segHi, oLo, sLo, oHi, sHi;
};

__device__ __forceinline__ void loadMeta(int p, PairMeta& M,
                                         const int* __restrict__ offs) {
  M.segLo = p;
  M.segHi = NSEG - 1 - p;
  M.oLo = offs[M.segLo]; M.sLo = offs[M.segLo + 1] - M.oLo;
  M.oHi = offs[M.segHi]; M.sHi = offs[M.segHi + 1] - M.oHi;
}

// Scalar prefetch: edge id -> neighbor row + iou (2 VGPR).
__device__ __forceinline__ void prefetchEdge(
    const PairMeta& M, int c, const int* __restrict__ nbrIdx,
    const float* __restrict__ iou, int n32, int& nbrow, float& io) {
  const int grow = (c << 5) + n32;
  const int e = pairEdge(grow, M.oLo, M.sLo, M.oHi, M.sHi);
  nbrow = nbrIdx[e];
  io = iou[e];
}

__device__ __forceinline__ void prefetchHm(
    const PairMeta& M, const float* __restrict__ Hm, int n32,
    float* hmLo, float* hmHi) {
#pragma unroll
  for (int q = 0; q < 4; ++q) {
    hmLo[q] = Hm[(long)M.segLo * HH + q * 32 + n32];
    hmHi[q] = Hm[(long)M.segHi * HH + q * 32 + n32];
  }
}

// ks=9 of the K dimension (k=144..159) is identically zero on BOTH operands
// (A pack zeroes k>=129; tab cols 144..159 are pad) -> 9 frags, not 10.
__device__ __forceinline__ void gatherX(const unsigned short* __restrict__ tab,
                                        int nbrow, int half, s16x8* X) {
  const unsigned short* ar = tab + (long)nbrow * 160;
#pragma unroll
  for (int ks = 0; ks < 9; ++ks)
    X[ks] = *(const s16x8*)(ar + ks * 16 + half * 8);
}

// GEMM1 + bias MFMA + relu + in-register transpose to GEMM2 A-fragments.
// C layout (32x32): col=lane&31 (edge), row=(reg&3)+8(reg>>2)+4*half (feat).
// cvt_pk pairs + 4 v_permlane32_swap_b32 per Mblk redistribute the
// half-wave k-groups into A2[ks][i] = H[edge=lane&31][k=16ks+8*half+i].
__device__ __forceinline__ void gemm1Phase(
    const PairMeta& M, int c, const s16x8* X, float io,
    const short* __restrict__ As1, const float* wvT,
    const float* hmLo, const float* hmHi,
    int lane, int half, int n32, s16x8* A2) {
  const int grow = (c << 5) + n32;
  const short oneBf = (short)0x3F80;
  s16x8 bb = (s16x8){0, 0, 0, 0, 0, 0, 0, 0};
  if (half == 0) {
    const bool lo = grow < M.sLo;
    bb[0] = lo ? oneBf : (short)0;
    bb[1] = bb[0];
    bb[2] = lo ? (short)0 : oneBf;
    bb[3] = bb[2];
    bb[4] = (short)f2bf(io);
  }
#pragma unroll
  for (int Mblk = 0; Mblk < 4; ++Mblk) {
    f32x16 C;
#pragma unroll
    for (int i = 0; i < 16; ++i) C[i] = 0.f;
#pragma unroll
    for (int ks = 0; ks < 9; ++ks) {
      const s16x8 a = *(const s16x8*)(As1 + ((Mblk * 10 + ks) * 64 + lane) * 8);
      C = __builtin_amdgcn_mfma_f32_32x32x16_bf16(a, X[ks], C, 0, 0, 0);
    }
    s16x8 ab = (s16x8){0, 0, 0, 0, 0, 0, 0, 0};
    if (half == 0) {
      const unsigned short p0 = f2bf(hmLo[Mblk]);
      ab[0] = (short)p0;
      ab[1] = (short)f2bf(hmLo[Mblk] - bf2f(p0));
      const unsigned short p1 = f2bf(hmHi[Mblk]);
      ab[2] = (short)p1;
      ab[3] = (short)f2bf(hmHi[Mblk] - bf2f(p1));
      ab[4] = (short)f2bf(wvT[Mblk]);
    }
    C = __builtin_amdgcn_mfma_f32_32x32x16_bf16(ab, bb, C, 0, 0, 0);
    unsigned wv[8];
#pragma unroll
    for (int j = 0; j < 8; ++j) {
      const float lo = fmaxf(C[2 * j], 0.f);
      const float hi = fmaxf(C[2 * j + 1], 0.f);
      asm("v_cvt_pk_bf16_f32 %0, %1, %2" : "=v"(wv[j]) : "v"(lo), "v"(hi));
    }
    asm("v_permlane32_swap_b32 %0, %1" : "+v"(wv[0]), "+v"(wv[2]));
    asm("v_permlane32_swap_b32 %0, %1" : "+v"(wv[1]), "+v"(wv[3]));
    asm("v_permlane32_swap_b32 %0, %1" : "+v"(wv[4]), "+v"(wv[6]));
    asm("v_permlane32_swap_b32 %0, %1" : "+v"(wv[5]), "+v"(wv[7]));
    union { u32x4 u; s16x8 s; } q0, q1;
    q0.u = (u32x4){wv[0], wv[1], wv[2], wv[3]};
    q1.u = (u32x4){wv[4], wv[5], wv[6], wv[7]};
    A2[2 * Mblk] = q0.s;
    A2[2 * Mblk + 1] = q1.s;
  }
}

// GEMM2 + masked segment-split max update (A-fragments come in registers)
__device__ __forceinline__ void gemm2Phase(
    const PairMeta& M, int c, const s16x8* A2, const short* __restrict__ Bs2,
    int lane, int half, int n32, float* mxLo, float* mxHi) {
#pragma unroll
  for (int nb = 0; nb < 4; ++nb) {
    f32x16 D;
#pragma unroll
    for (int i = 0; i < 16; ++i) D[i] = 0.f;
#pragma unroll
    for (int ks = 0; ks < 8; ++ks) {
      const s16x8 b = *(const s16x8*)(Bs2 + ((ks * 4 + nb) * 64 + lane) * 8);
      D = __builtin_amdgcn_mfma_f32_32x32x16_bf16(A2[ks], b, D, 0, 0, 0);
    }
#pragma unroll
    for (int reg = 0; reg < 16; ++reg) {
      const int rrow = (reg & 3) + 8 * (reg >> 2) + 4 * half;
      const int gr = (c << 5) + rrow;
      const float v = D[reg];
      if (gr < M.sLo) mxLo[nb] = fmaxf(mxLo[nb], v);
      else            mxHi[nb] = fmaxf(mxHi[nb], v);
    }
  }
}

// ---------------------------------------------------------------------------
// edge_kernel (32x32x16 MFMA): one segment PAIR = one 32-edge M-tile.
// (512,2), zero spill, grid 248 = 1 block/CU, 4 pairs/wave.
// TWO-DEEP scalar pipeline: nbrow/io for pair p+1 are loaded one full pair
// EARLY (during pair p-1), so gatherX(p+1) issues immediately after
// GEMM1(p) kills X — no nbrIdx->gather serial chain on the critical path.
// loadMeta/prefetchEdge for p+2 issue concurrently with that gather.
// Exposed latency per pair: max(gather, GEMM2) instead of nbr+gather.
// ---------------------------------------------------------------------------
__global__ __launch_bounds__(512, 2) void edge_kernel(
    const unsigned short* __restrict__ tab, const short* __restrict__ PA1,
    const short* __restrict__ PB2, const float* __restrict__ W1,
    const float* __restrict__ Hm, const float* __restrict__ iou,
    const int* __restrict__ nbrIdx, const int* __restrict__ offs,
    const float* __restrict__ b2, unsigned short* __restrict__ pooled) {
  extern __shared__ __align__(16) char smem[];
  short* As1 = (short*)smem;               // 40960 B
  short* Bs2 = (short*)(smem + 40960);     // 32768 B
  {
    const f32x4* s1 = (const f32x4*)PA1;
    f32x4* d1 = (f32x4*)As1;
    for (int i = threadIdx.x; i < 2560; i += 512) d1[i] = s1[i];
    const f32x4* s2 = (const f32x4*)PB2;
    f32x4* d2 = (f32x4*)Bs2;
    for (int i = threadIdx.x; i < 2048; i += 512) d2[i] = s2[i];
  }
  __syncthreads();

  const int lane = threadIdx.x & 63;
  const int w = __builtin_amdgcn_readfirstlane(threadIdx.x >> 6);
  const int half = lane >> 5, n32 = lane & 31;

  float b2v[4], wvT[4];
#pragma unroll
  for (int q = 0; q < 4; ++q) {
    b2v[q] = b2[q * 32 + n32];
    wvT[q] = W1[258 * HH + q * 32 + n32];
  }

  const int wid = (blockIdx.x << 3) + w;   // SGPR
  const int nw = gridDim.x << 3;
  const int npairs = NSEG >> 1;

  if (wid >= npairs) return;

  PairMeta M, M1, M2;
  int nb1, nb2;
  float io, io1, io2;
  float hmLo[4], hmHi[4];
  s16x8 X[9];
  // prologue: pair p0 fully staged; pair p0+nw scalar-staged
  loadMeta(wid, M, offs);
  {
    int nb0;
    prefetchEdge(M, 0, nbrIdx, iou, n32, nb0, io);
    gatherX(tab, nb0, half, X);
  }
  prefetchHm(M, Hm, n32, hmLo, hmHi);
  if (wid + nw < npairs) {
    loadMeta(wid + nw, M1, offs);
    prefetchEdge(M1, 0, nbrIdx, iou, n32, nb1, io1);
  }

  int p = wid;
  for (;;) {
    const int pn1 = p + nw, pn2 = p + 2 * nw;
    const bool h1 = pn1 < npairs, h2 = pn2 < npairs;
    s16x8 A2[8];
    gemm1Phase(M, 0, X, io, As1, wvT, hmLo, hmHi, lane, half, n32, A2);
    // X/io/hm dead for pair p
    const bool small = (M.sLo + M.sHi) <= 32;
    if (small && h1) {
      gatherX(tab, nb1, half, X);           // issues NOW (nb1 preloaded)
      prefetchHm(M1, Hm, n32, hmLo, hmHi);  // in-place (hm dead)
      if (h2) {                             // scalar stage for p+2
        loadMeta(pn2, M2, offs);
        prefetchEdge(M2, 0, nbrIdx, iou, n32, nb2, io2);
      }
    }
    float mxLo[4], mxHi[4];
#pragma unroll
    for (int q = 0; q < 4; ++q) { mxLo[q] = -3.4e38f; mxHi[q] = -3.4e38f; }
    gemm2Phase(M, 0, A2, Bs2, lane, half, n32, mxLo, mxHi);
    if (!small) {
      // cold multi-chunk fallback: X/A2 free here (refill deferred)
      const int nchunk = (M.sLo + M.sHi + 31) >> 5;
      for (int c = 1; c < nchunk; ++c) {
        int nbf; float iof;
        prefetchEdge(M, c, nbrIdx, iou, n32, nbf, iof);
        gatherX(tab, nbf, half, X);
        gemm1Phase(M, c, X, iof, As1, wvT, hmLo, hmHi, lane, half, n32, A2);
        gemm2Phase(M, c, A2, Bs2, lane, half, n32, mxLo, mxHi);
      }
      if (h1) {  // deferred refill for p+1 (+ scalar stage for p+2)
        gatherX(tab, nb1, half, X);
        prefetchHm(M1, Hm, n32, hmLo, hmHi);
        if (h2) {
          loadMeta(pn2, M2, offs);
          prefetchEdge(M2, 0, nbrIdx, iou, n32, nb2, io2);
        }
      }
    }
#pragma unroll
    for (int nb = 0; nb < 4; ++nb) {
      float lo = fmaxf(mxLo[nb], __shfl_xor(mxLo[nb], 32, 64));
      float hi = fmaxf(mxHi[nb], __shfl_xor(mxHi[nb], 32, 64));
      if (half == 0) {
        pooled[(long)M.segLo * HH + nb * 32 + n32] = f2bf(fmaxf(lo + b2v[nb], 0.f));
        pooled[(long)M.segHi * HH + nb * 32 + n32] = f2bf(fmaxf(hi + b2v[nb], 0.f));
      }
    }
    if (!h1) break;
    M = M1; io = io1;
    if (h2) { M1 = M2; nb1 = nb2; io1 = io2; }
    p = pn1;
  }
}

// ---------------------------------------------------------------------------
// resout: RES = resIn + bo + pooled @ Wo (16x16 MFMA). Then via bf16 bounce:
//   NEXT=1: write resOut fp32 + TAB bf16 and compute HM_next = b1n + res@W1m.
//   NEXT=0: fused final head out = relu(res@fW1+fb1)@fW2 + fb2.
// ---------------------------------------------------------------------------
template <int NEXT>
__global__ __launch_bounds__(256) void resout_kernel(
    const unsigned short* __restrict__ pooled, const short* __restrict__ PWo,
    const float* __restrict__ bo, const float* __restrict__ resIn,
    float* __restrict__ resOut, unsigned short* __restrict__ tab,
    const short* __restrict__ PW1mN, const float* __restrict__ b1n,
    float* __restrict__ HmOut,
    const short* __restrict__ PfW1, const float* __restrict__ fb1,
    const float* __restrict__ fW2, const float* __restrict__ fb2,
    float* __restrict__ outFinal) {
  __shared__ short stS[4][16 * 168];
  const int lane = threadIdx.x & 63, w = threadIdx.x >> 6;
  const int lk = lane >> 4, n16 = lane & 15;
  short* st = stS[w];

  {
    const int row = lane >> 2, c0 = 129 + (lane & 3) * 8;
#pragma unroll
    for (int i = 0; i < 8; ++i) st[row * 168 + c0 + i] = 0;
  }

  const int tile = blockIdx.x * 4 + w;
  const unsigned short* arow = pooled + (long)(tile * 16 + n16) * HH;
  s16x8 A[4];
#pragma unroll
  for (int ks = 0; ks < 4; ++ks) A[ks] = *(const s16x8*)(arow + ks * 32 + lk * 8);
  f32x4 C[9];
#pragma unroll
  for (int nf = 0; nf < 9; ++nf) C[nf] = (f32x4){0.f, 0.f, 0.f, 0.f};
#pragma unroll
  for (int ks = 0; ks < 4; ++ks)
#pragma unroll
    for (int nf = 0; nf < 9; ++nf) {
      const s16x8 b = *(const s16x8*)(PWo + (((ks * 4 + lk) * 144) + nf * 16 + n16) * 8);
      C[nf] = __builtin_amdgcn_mfma_f32_16x16x32_bf16(A[ks], b, C[nf], 0, 0, 0);
    }

#pragma unroll
  for (int nf = 0; nf < 8; ++nf) {
    const int col = nf * 16 + n16;
    const float bov = bo[col];
#pragma unroll
    for (int r = 0; r < 4; ++r) {
      const int row = lk * 4 + r;
      const long node = tile * 16 + row;
      const float res = resIn[node * DD + col] + bov + C[nf][r];
      if (NEXT) {
        resOut[node * DD + col] = res;
        tab[node * 160 + col] = f2bf(res);
      }
      st[row * 168 + col] = (short)f2bf(res);
    }
  }
  if (n16 == 0) {
#pragma unroll
    for (int r = 0; r < 4; ++r) {
      const int row = lk * 4 + r;
      const long node = tile * 16 + row;
      const float res = resIn[node * DD + 128] + bo[128] + C[8][r];
      if (NEXT) {
        resOut[node * DD + 128] = res;
        tab[node * 160 + 128] = f2bf(res);
      }
      st[row * 168 + 128] = (short)f2bf(res);
    }
  }

  s16x8 A5[5];
#pragma unroll
  for (int ks = 0; ks < 5; ++ks)
    A5[ks] = *(const s16x8*)(st + n16 * 168 + ks * 32 + lk * 8);

  if (NEXT) {
    f32x4 H[8];
#pragma unroll
    for (int nf = 0; nf < 8; ++nf) H[nf] = (f32x4){0.f, 0.f, 0.f, 0.f};
#pragma unroll
    for (int ks = 0; ks < 5; ++ks)
#pragma unroll
      for (int nf = 0; nf < 8; ++nf) {
        const s16x8 b = *(const s16x8*)(PW1mN + (((ks * 4 + lk) * 128) + nf * 16 + n16) * 8);
        H[nf] = __builtin_amdgcn_mfma_f32_16x16x32_bf16(A5[ks], b, H[nf], 0, 0, 0);
      }
#pragma unroll
    for (int nf = 0; nf < 8; ++nf) {
      const float bv = b1n[nf * 16 + n16];
#pragma unroll
      for (int r = 0; r < 4; ++r)
        HmOut[(long)(tile * 16 + lk * 4 + r) * HH + nf * 16 + n16] = H[nf][r] + bv;
    }
  } else {
    f32x4 Ch[4];
#pragma unroll
    for (int nf = 0; nf < 4; ++nf) Ch[nf] = (f32x4){0.f, 0.f, 0.f, 0.f};
#pragma unroll
    for (int ks = 0; ks < 5; ++ks)
#pragma unroll
      for (int nf = 0; nf < 4; ++nf) {
        const s16x8 b = *(const s16x8*)(PfW1 + (((ks * 4 + lk) * 64) + nf * 16 + n16) * 8);
        Ch[nf] = __builtin_amdgcn_mfma_f32_16x16x32_bf16(A5[ks], b, Ch[nf], 0, 0, 0);
      }
    float b1v[4], w2v[4];
#pragma unroll
    for (int nf = 0; nf < 4; ++nf) {
      b1v[nf] = fb1[nf * 16 + n16];
      w2v[nf] = fW2[nf * 16 + n16];
    }
#pragma unroll
    for (int r = 0; r < 4; ++r) {
      float s = 0.f;
#pragma unroll
      for (int nf = 0; nf < 4; ++nf)
        s += fmaxf(Ch[nf][r] + b1v[nf], 0.f) * w2v[nf];
      s += __shfl_xor(s, 1, 64);
      s += __shfl_xor(s, 2, 64);
      s += __shfl_xor(s, 4, 64);
      s += __shfl_xor(s, 8, 64);
      if (n16 == 0) outFinal[tile * 16 + lk * 4 + r] = s + fb2[0];
    }
  }
}

// ---------------------------------------------------------------------------
extern "C" void kernel_launch(void* const* d_in, const int* in_sizes, int n_in,
                              void* d_out, int out_size, void* d_ws, size_t ws_size,
                              hipStream_t stream) {
  const float* interp  = (const float*)d_in[0];
  const float* addInfo = (const float*)d_in[1];
  const int* sizes     = (const int*)d_in[2];
  const int* nbrIdx    = (const int*)d_in[3];
  const float* b0W1 = (const float*)d_in[5];
  const float* b0b1 = (const float*)d_in[6];
  const float* b0W2 = (const float*)d_in[7];
  const float* b0b2 = (const float*)d_in[8];
  const float* b0Wo = (const float*)d_in[9];
  const float* b0bo = (const float*)d_in[10];
  const float* b1W1 = (const float*)d_in[11];
  const float* b1b1 = (const float*)d_in[12];
  const float* b1W2 = (const float*)d_in[13];
  const float* b1b2 = (const float*)d_in[14];
  const float* b1Wo = (const float*)d_in[15];
  const float* b1bo = (const float*)d_in[16];
  const float* fW1  = (const float*)d_in[17];
  const float* fb1  = (const float*)d_in[18];
  const float* fW2  = (const float*)d_in[19];
  const float* fb2  = (const float*)d_in[20];

  char* ws = (char*)d_ws;
  int*            offs  = (int*)(ws + 0);                    // 65536
  short*          PA1   = (short*)(ws + 65536);              // 81920
  short*          PB2   = (short*)(ws + 147456);             // 65536
  short*          PWo   = (short*)(ws + 212992);             // 73728
  short*          PW1m  = (short*)(ws + 286720);             // 81920
  short*          PfW1  = (short*)(ws + 368640);             // 20480 -> pad
  unsigned short* TAB   = (unsigned short*)(ws + 393216);    // N*160*2
  float*          HM    = (float*)(ws + 5472256);            // N*128*4
  unsigned short* POOLED= (unsigned short*)(ws + 13598720);  // N*128*2
  float*          RES   = (float*)(ws + 17661952);           // N*129*4

  // pack + tab + fused hmprep + fused scan: one dispatch
  pack_tab_kernel<<<PTBLK + HMBLK + 1, 256, 0, stream>>>(
      interp, TAB, b0W1, b1W1, b0W2, b1W2, b0Wo, b1Wo, fW1,
      PA1, PB2, PWo, PW1m, PfW1, b0b1, HM, sizes, offs);

  const size_t e_lds = 40960 + 32768;  // 73728

  // ---- block 0 ----
  edge_kernel<<<248, 512, e_lds, stream>>>(TAB, PA1, PB2, b0W1, HM, addInfo,
                                           nbrIdx, offs, b0b2, POOLED);
  resout_kernel<1><<<NTILE / 4, 256, 0, stream>>>(
      POOLED, PWo, b0bo, interp, RES, TAB, PW1m + 20480, b1b1, HM,
      nullptr, nullptr, nullptr, nullptr, nullptr);

  // ---- block 1 ----
  edge_kernel<<<248, 512, e_lds, stream>>>(TAB, PA1 + 20480, PB2 + 16384, b1W1,
                                           HM, addInfo, nbrIdx, offs,
                                           b1b2, POOLED);
  resout_kernel<0><<<NTILE / 4, 256, 0, stream>>>(
      POOLED, PWo + 18432, b1bo, RES, nullptr, nullptr, nullptr, nullptr,
      nullptr, PfW1, fb1, fW2, fb2, (float*)d_out);
}